// Round 1
// baseline (5872.734 us; speedup 1.0000x reference)
//
#include <hip/hip_runtime.h>

// SDGraphUNet on MI355X — round 0: correct fp32 implementation.
//
// Pipeline:
//  k_build_xt     : union_dense features -> xt[4][8192][96] (point-major)
//  k_x2           : fp32 squared norms (pass-1 scoring only)
//  k_sparse_union : union_sparse features -> xtsp[4][32][96]
//  k_sparse_gcn   : k=2 GCN over strokes -> d_out[0..16384)
//  k_g1p1         : EdgeConv factorization g1[j][110], p1[q][110]
//  k_knn1         : approx top-64 by s = 2*dot - |xj|^2 (fp32, margin 14)
//  k_rerank       : exact fp64 rerank of the 64 -> exact top-50 set
//  k_econv        : per-(q,neighbor) leaky(g1+p1) @ W2 -> max over 50
//  k_down         : conv (1,3) stride (1,2) pad (0,1) + leaky -> d_out[16384..)
//
// ws layout (floats): xt 3145728 | x2 32768 | g1 3604480 | p1 3604480 |
//   i64 2097152(int) | i50 1638400(int) | cin 2097152 | xtsp 12288
//   total 16,232,448 floats = 64.9 MB

#define LEAKK 0.2f
#define KSEL 64

__device__ __forceinline__ float leaky(float x){ return x > 0.f ? x : LEAKK*x; }

// ---------------- build dense union features ----------------
__global__ void k_build_xt(const float* __restrict__ dense, const float* __restrict__ sparse,
                           float* __restrict__ xt){
  int t = blockIdx.x*256 + threadIdx.x;       // < 4*8192*96
  int c = t % 96;
  int rest = t / 96;
  int p = rest & 8191;
  int b = rest >> 13;
  int s = p >> 8, pp = p & 255;
  float v;
  if (c < 32) v = dense[(((b*32 + c)*32 + s) << 8) + pp];
  else        v = sparse[(b*64 + (c - 32))*32 + s];
  xt[t] = v;
}

__global__ void k_x2(const float* __restrict__ xt, float* __restrict__ x2){
  int p = blockIdx.x*256 + threadIdx.x;       // < 32768
  const float4* r = (const float4*)(xt + (size_t)p*96);
  float a0=0.f, a1=0.f;
  #pragma unroll
  for (int k = 0; k < 24; k += 2){
    float4 v = r[k]; float4 u = r[k+1];
    a0 += v.x*v.x + v.y*v.y + v.z*v.z + v.w*v.w;
    a1 += u.x*u.x + u.y*u.y + u.z*u.z + u.w*u.w;
  }
  x2[p] = a0 + a1;
}

// ---------------- sparse union (max over points + concat) ----------------
__global__ void k_sparse_union(const float* __restrict__ sp, const float* __restrict__ dn,
                               float* __restrict__ xtsp){
  int b = blockIdx.x >> 5, i = blockIdx.x & 31;
  int w = threadIdx.x >> 6, l = threadIdx.x & 63;
  if (w == 0) xtsp[(b*32 + i)*96 + l] = sp[(b*64 + l)*32 + i];   // l<64 channels 0..63
  for (int c = w; c < 32; c += 4){
    const float* row = dn + (((size_t)(b*32 + c)*32 + i) << 8);
    float v = fmaxf(fmaxf(row[l], row[l+64]), fmaxf(row[l+128], row[l+192]));
    for (int off = 32; off > 0; off >>= 1) v = fmaxf(v, __shfl_down(v, off));
    if (l == 0) xtsp[(b*32 + i)*96 + 64 + c] = v;
  }
}

// ---------------- sparse GCN (k=2 over 32 strokes) ----------------
__global__ void k_sparse_gcn(const float* __restrict__ xtsp,
                             const float* __restrict__ W1, const float* __restrict__ bb1,
                             const float* __restrict__ W2, const float* __restrict__ bb2,
                             float* __restrict__ outp){
  int b = blockIdx.x >> 5, i = blockIdx.x & 31, t = threadIdx.x;
  __shared__ float X[32*96];
  __shared__ float x2l[32], dd[32];
  __shared__ int nb[2];
  for (int k = t; k < 3072; k += 192) X[k] = xtsp[b*3072 + k];
  __syncthreads();
  if (t < 32){
    float s = 0.f;
    for (int c = 0; c < 96; ++c){ float v = X[t*96+c]; s += v*v; }
    x2l[t] = s;
  }
  __syncthreads();
  if (t < 32){
    float dot = 0.f;
    for (int c = 0; c < 96; ++c) dot += X[i*96+c]*X[t*96+c];
    dd[t] = x2l[i] - 2.f*dot + x2l[t];
  }
  __syncthreads();
  if (t == 0){
    int s0 = -1, s1 = -1;
    for (int j = 0; j < 32; ++j){
      float dj = dd[j];
      if (s0 < 0 || dj < dd[s0]){ s1 = s0; s0 = j; }
      else if (s1 < 0 || dj < dd[s1]){ s1 = j; }
    }
    nb[0] = s0; nb[1] = s1;
  }
  __syncthreads();
  __shared__ __align__(16) float E[192];
  __shared__ __align__(16) float H1[156];
  float acc = -3.4e38f;
  for (int n = 0; n < 2; ++n){
    int j = nb[n];
    if (t < 96){ E[t] = X[j*96+t] - X[i*96+t]; E[96+t] = X[i*96+t]; }
    __syncthreads();
    if (t < 156){
      float h = bb1[t];
      const float* wr = W1 + t*192;
      for (int k = 0; k < 192; ++k) h += E[k]*wr[k];
      H1[t] = leaky(h);
    }
    __syncthreads();
    if (t < 128){
      float h = bb2[t];
      const float* wr = W2 + t*156;
      for (int m = 0; m < 156; ++m) h += H1[m]*wr[m];
      acc = fmaxf(acc, leaky(h));
    }
    __syncthreads();
  }
  if (t < 128) outp[(b*128 + t)*32 + i] = acc;
}

// ---------------- EdgeConv factorization: g1, p1 ----------------
__global__ void k_g1p1(const float* __restrict__ xt, const float* __restrict__ W1,
                       const float* __restrict__ bb1,
                       float* __restrict__ g1, float* __restrict__ p1){
  __shared__ float xl[8*96];
  int p0 = blockIdx.x*8;                      // global point base
  int t = threadIdx.x;
  for (int k = t; k < 768; k += 256) xl[k] = xt[(size_t)p0*96 + k];
  __syncthreads();
  for (int oi = t; oi < 880; oi += 256){
    int pi = oi/110, m = oi - pi*110;
    const float* wr = W1 + m*192;
    float a = 0.f, c2 = 0.f;
    for (int c = 0; c < 96; ++c){ float xv = xl[pi*96+c]; a += wr[c]*xv; c2 += wr[96+c]*xv; }
    g1[(size_t)(p0+pi)*110 + m] = a;
    p1[(size_t)(p0+pi)*110 + m] = c2 - a + bb1[m];
  }
}

// ---------------- dense kNN pass 1: approx top-64 ----------------
// 2 threads per query (c-split); one wave's even lanes own 32 query columns.
__global__ __launch_bounds__(128) void k_knn1(const float* __restrict__ xt,
                                              const float* __restrict__ x2,
                                              int* __restrict__ idx64){
  int b = blockIdx.x >> 7, qc = blockIdx.x & 127;
  int t = threadIdx.x;
  int col = t >> 1, half = t & 1;
  int q = qc*64 + col;
  int gq = b*8192 + q;
  __shared__ float S[KSEL][64];
  __shared__ unsigned short J[KSEL][64];
  __shared__ float GM[8][64];
  if (!half){
    for (int k = 0; k < KSEL; ++k){ S[k][col] = -3.4e38f; J[k][col] = 0; }
    for (int g = 0; g < 8; ++g) GM[g][col] = -3.4e38f;
  }
  __syncthreads();
  float4 qv[12];
  const float4* qp = (const float4*)(xt + (size_t)gq*96) + half*12;
  #pragma unroll
  for (int k = 0; k < 12; ++k) qv[k] = qp[k];
  const float* xb = xt + (size_t)b*8192*96;
  const float* x2b = x2 + b*8192;
  float root = -3.4e38f; int rootg = 0;
  #pragma unroll 1
  for (int j = 0; j < 8192; ++j){
    const float4* cr = (const float4*)(xb + (size_t)j*96) + half*12;
    float a0=0.f,a1=0.f,a2=0.f,a3=0.f;
    #pragma unroll
    for (int k = 0; k < 3; ++k){
      float4 c0 = cr[4*k+0], c1 = cr[4*k+1], c2 = cr[4*k+2], c3 = cr[4*k+3];
      a0 += qv[4*k+0].x*c0.x + qv[4*k+0].y*c0.y + qv[4*k+0].z*c0.z + qv[4*k+0].w*c0.w;
      a1 += qv[4*k+1].x*c1.x + qv[4*k+1].y*c1.y + qv[4*k+1].z*c1.z + qv[4*k+1].w*c1.w;
      a2 += qv[4*k+2].x*c2.x + qv[4*k+2].y*c2.y + qv[4*k+2].z*c2.z + qv[4*k+2].w*c2.w;
      a3 += qv[4*k+3].x*c3.x + qv[4*k+3].y*c3.y + qv[4*k+3].z*c3.z + qv[4*k+3].w*c3.w;
    }
    float part = a0+a1+a2+a3;
    part += __shfl_xor(part, 1);
    float s = 2.f*part - x2b[j];
    if (!half && s > root){
      int base = rootg << 3;
      float mn = S[base][col]; int mi = base;
      #pragma unroll
      for (int k = 1; k < 8; ++k){ float v = S[base+k][col]; if (v < mn){ mn = v; mi = base+k; } }
      S[mi][col] = s; J[mi][col] = (unsigned short)j;
      mn = 3.4e38f;
      #pragma unroll
      for (int k = 0; k < 8; ++k) mn = fminf(mn, S[base+k][col]);
      GM[rootg][col] = mn;
      root = GM[0][col]; rootg = 0;
      #pragma unroll
      for (int g = 1; g < 8; ++g){ float v = GM[g][col]; if (v < root){ root = v; rootg = g; } }
    }
  }
  if (!half){
    for (int k = 0; k < KSEL; ++k) idx64[(size_t)gq*KSEL + k] = (int)J[k][col];
  }
}

// ---------------- dense kNN pass 2: exact fp64 rerank -> top-50 set ----------------
__global__ __launch_bounds__(64) void k_rerank(const float* __restrict__ xt,
                                               const int* __restrict__ idx64,
                                               int* __restrict__ idx50){
  int t = threadIdx.x;
  int gq = blockIdx.x*64 + t;
  int b = gq >> 13;
  __shared__ double DU[KSEL][64];
  __shared__ int    JU[KSEL][64];
  const float* xq = xt + (size_t)gq*96;
  float qf[96];
  #pragma unroll
  for (int c = 0; c < 96; ++c) qf[c] = xq[c];
  double x2q = 0.0;
  #pragma unroll
  for (int c = 0; c < 96; ++c){ double v = (double)qf[c]; x2q += v*v; }
  const float* xb = xt + (size_t)b*8192*96;
  for (int k = 0; k < KSEL; ++k){
    int j = idx64[(size_t)gq*KSEL + k];
    const float* cr = xb + (size_t)j*96;
    double dot = 0.0, x2j = 0.0;
    #pragma unroll
    for (int c = 0; c < 96; ++c){
      double xv = (double)cr[c];
      dot += xv*(double)qf[c];
      x2j += xv*xv;
    }
    DU[k][t] = x2q + x2j - 2.0*dot;   // exactly 0 for j==gq (same summation order)
    JU[k][t] = j;
  }
  // remove the 14 worst (largest d; tie -> larger index is worse, matching stable top_k)
  for (int r = 0; r < KSEL-50; ++r){
    double best = -1.0; int bj = -1, bk = 0;
    for (int k = 0; k < KSEL; ++k){
      double d = DU[k][t]; int j = JU[k][t];
      if (d > best || (d == best && j > bj)){ best = d; bj = j; bk = k; }
    }
    DU[bk][t] = -1.0;
  }
  int cnt = 0;
  for (int k = 0; k < KSEL; ++k){
    if (DU[k][t] >= 0.0){ idx50[(size_t)gq*50 + cnt] = JU[k][t]; ++cnt; }
  }
}

// ---------------- dense EdgeConv W2 GEMM + max over 50 neighbors ----------------
__global__ __launch_bounds__(64) void k_econv(const float* __restrict__ g1,
                                              const float* __restrict__ p1,
                                              const int* __restrict__ idx50,
                                              const float* __restrict__ W2,
                                              const float* __restrict__ bb2,
                                              float* __restrict__ cin){
  int gq = blockIdx.x;
  int b = gq >> 13;
  int l = threadIdx.x;
  float w2[110];
  #pragma unroll
  for (int m = 0; m < 110; ++m) w2[m] = W2[l*110 + m];   // lane l = out channel
  float pA = p1[(size_t)gq*110 + l];
  float pB = (l < 46) ? p1[(size_t)gq*110 + 64 + l] : 0.f;
  float bias = bb2[l];
  __shared__ __align__(16) float tb[112];
  float omax = -3.4e38f;
  for (int n = 0; n < 50; ++n){
    int j = idx50[(size_t)gq*50 + n];
    size_t gj = (size_t)(b*8192 + j)*110;
    float gA = g1[gj + l];
    float gB = (l < 46) ? g1[gj + 64 + l] : 0.f;
    __syncthreads();                       // tb from previous iter fully read
    tb[l] = leaky(gA + pA);
    if (l < 46) tb[64 + l] = leaky(gB + pB);
    __syncthreads();
    float acc = bias;
    #pragma unroll
    for (int m = 0; m < 110; ++m) acc += w2[m]*tb[m];
    omax = fmaxf(omax, leaky(acc));
  }
  cin[(size_t)gq*64 + l] = omax;           // cin layout [b][p][o] (coalesced)
}

// ---------------- downsample conv (1,3) stride (1,2) pad (0,1) ----------------
__global__ void k_down(const float* __restrict__ cin, const float* __restrict__ Wd,
                       const float* __restrict__ bias, float* __restrict__ outp){
  int b = blockIdx.x >> 6; int r = blockIdx.x & 63;
  int s = r >> 1; int ph = r & 1;
  int t = threadIdx.x;
  __shared__ float L[130*65];               // [rr][i], padded
  for (int k = t; k < 130*64; k += 256){
    int rr = k >> 6, i = k & 63;
    int pp = ph*128 - 1 + rr;
    float v = 0.f;
    if (pp >= 0 && pp < 256) v = cin[(size_t)((b*8192 + s*256 + pp))*64 + i];
    L[rr*65 + i] = v;
  }
  __syncthreads();
  for (int ow = t; ow < 4096; ow += 256){
    int o = ow >> 6, wl = ow & 63;
    int w = ph*64 + wl;
    float acc = bias[o];
    #pragma unroll
    for (int tt = 0; tt < 3; ++tt){
      int rr = 2*wl + tt;
      const float* wr = Wd + o*192 + tt;    // Wd[(o*64+i)*3+tt]
      for (int i = 0; i < 64; ++i) acc += L[rr*65 + i]*wr[i*3];
    }
    outp[16384 + ((size_t)((b*64 + o)*32 + s))*128 + w] = leaky(acc);
  }
}

extern "C" void kernel_launch(void* const* d_in, const int* in_sizes, int n_in,
                              void* d_out, int out_size, void* d_ws, size_t ws_size,
                              hipStream_t stream){
  (void)in_sizes; (void)n_in; (void)out_size; (void)ws_size;
  const float* sparse = (const float*)d_in[0];
  const float* dense  = (const float*)d_in[1];
  const float* spW1   = (const float*)d_in[2];
  const float* spb1   = (const float*)d_in[3];
  const float* spW2   = (const float*)d_in[4];
  const float* spb2   = (const float*)d_in[5];
  const float* dnW1   = (const float*)d_in[6];
  const float* dnb1   = (const float*)d_in[7];
  const float* dnW2   = (const float*)d_in[8];
  const float* dnb2   = (const float*)d_in[9];
  const float* dsW    = (const float*)d_in[10];
  const float* dsb    = (const float*)d_in[11];
  float* out = (float*)d_out;

  float* w    = (float*)d_ws;               // needs 64.93 MB
  float* xt   = w;
  float* x2   = w + 3145728;
  float* g1   = w + 3178496;
  float* p1   = w + 6782976;
  int*   i64  = (int*)(w + 10387456);
  int*   i50  = (int*)(w + 12484608);
  float* cin  = w + 14123008;
  float* xtsp = w + 16220160;

  k_build_xt   <<<12288, 256, 0, stream>>>(dense, sparse, xt);
  k_x2         <<<128,   256, 0, stream>>>(xt, x2);
  k_sparse_union<<<128,  256, 0, stream>>>(sparse, dense, xtsp);
  k_sparse_gcn <<<128,   192, 0, stream>>>(xtsp, spW1, spb1, spW2, spb2, out);
  k_g1p1       <<<4096,  256, 0, stream>>>(xt, dnW1, dnb1, g1, p1);
  k_knn1       <<<512,   128, 0, stream>>>(xt, x2, i64);
  k_rerank     <<<512,    64, 0, stream>>>(xt, i64, i50);
  k_econv      <<<32768,  64, 0, stream>>>(g1, p1, i50, dnW2, dnb2, cin);
  k_down       <<<256,   256, 0, stream>>>(cin, dsW, dsb, out);
}

// Round 2
// 2365.630 us; speedup vs baseline: 2.4825x; 2.4825x over previous
//
#include <hip/hip_runtime.h>

// SDGraphUNet on MI355X — round 1: MFMA-based kNN (histogram select + fp64 rerank).
//
// Pipeline:
//  k_build_xt     : union_dense -> xt fp32 [4][8192][96] + xtb bf16 (RNE)
//  k_x2           : fp32 squared norms
//  k_sparse_union : union_sparse -> xtsp[4][32][96]
//  k_sparse_gcn   : k=2 GCN over strokes -> d_out[0..16384)
//  k_histA        : MFMA score GEMM + per-query 256-bin LDS histogram -> thrF (rank-64 bin)
//  k_collectB     : MFMA score GEMM (bit-identical) + collect bin>=tb + fp64 rerank -> i50
//  k_g1p1         : EdgeConv factorization g1/p1 [32768][110]
//  k_econv        : leaky(g1+p1) @ W2 -> max over 50 -> cin
//  k_down         : conv (1,3) s(1,2) p(0,1) + leaky -> d_out[16384..)
//
// ws (floats): xt 3145728 | x2 32768 | g1 3604480 | p1 3604480 | i50 1638400(int)
//   | cin 2097152 | xtsp 12288 | xtb 1572864 (bf16 x 3145728) | thrF 32768
//   total 15,740,928 floats = 62.96 MB

#define LEAKK 0.2f

typedef short s16x8 __attribute__((ext_vector_type(8)));
typedef float f32x4 __attribute__((ext_vector_type(4)));

__device__ __forceinline__ float leaky(float x){ return x > 0.f ? x : LEAKK*x; }

// identical in both kNN passes -> bit-identical binning
__device__ __forceinline__ int score_bin(float acc, float x2c, float x2q){
  float s2 = __builtin_fmaf(2.f, acc, -x2c);   // 2*dot - |xc|^2
  float u  = (s2 - x2q) + 256.f;               // 256 - d_approx
  u = fminf(fmaxf(u, 0.f), 255.f);
  return (int)u;
}

// ---------------- build dense union features (fp32 + bf16) ----------------
__global__ void k_build_xt(const float* __restrict__ dense, const float* __restrict__ sparse,
                           float* __restrict__ xt, unsigned short* __restrict__ xtb){
  int t = blockIdx.x*256 + threadIdx.x;       // < 4*8192*96
  int c = t % 96;
  int rest = t / 96;
  int p = rest & 8191;
  int b = rest >> 13;
  int s = p >> 8, pp = p & 255;
  float v;
  if (c < 32) v = dense[(((b*32 + c)*32 + s) << 8) + pp];
  else        v = sparse[(b*64 + (c - 32))*32 + s];
  xt[t] = v;
  unsigned bits = __float_as_uint(v);
  unsigned r = (bits + 0x7FFFu + ((bits >> 16) & 1u)) >> 16;   // RNE to bf16
  xtb[t] = (unsigned short)r;
}

__global__ void k_x2(const float* __restrict__ xt, float* __restrict__ x2){
  int p = blockIdx.x*256 + threadIdx.x;       // < 32768
  const float4* r = (const float4*)(xt + (size_t)p*96);
  float a0=0.f, a1=0.f;
  #pragma unroll
  for (int k = 0; k < 24; k += 2){
    float4 v = r[k]; float4 u = r[k+1];
    a0 += v.x*v.x + v.y*v.y + v.z*v.z + v.w*v.w;
    a1 += u.x*u.x + u.y*u.y + u.z*u.z + u.w*u.w;
  }
  x2[p] = a0 + a1;
}

// ---------------- sparse union (max over points + concat) ----------------
__global__ void k_sparse_union(const float* __restrict__ sp, const float* __restrict__ dn,
                               float* __restrict__ xtsp){
  int b = blockIdx.x >> 5, i = blockIdx.x & 31;
  int w = threadIdx.x >> 6, l = threadIdx.x & 63;
  if (w == 0) xtsp[(b*32 + i)*96 + l] = sp[(b*64 + l)*32 + i];
  for (int c = w; c < 32; c += 4){
    const float* row = dn + (((size_t)(b*32 + c)*32 + i) << 8);
    float v = fmaxf(fmaxf(row[l], row[l+64]), fmaxf(row[l+128], row[l+192]));
    for (int off = 32; off > 0; off >>= 1) v = fmaxf(v, __shfl_down(v, off));
    if (l == 0) xtsp[(b*32 + i)*96 + 64 + c] = v;
  }
}

// ---------------- sparse GCN (k=2 over 32 strokes) ----------------
__global__ void k_sparse_gcn(const float* __restrict__ xtsp,
                             const float* __restrict__ W1, const float* __restrict__ bb1,
                             const float* __restrict__ W2, const float* __restrict__ bb2,
                             float* __restrict__ outp){
  int b = blockIdx.x >> 5, i = blockIdx.x & 31, t = threadIdx.x;
  __shared__ float X[32*96];
  __shared__ float x2l[32], dd[32];
  __shared__ int nb[2];
  for (int k = t; k < 3072; k += 192) X[k] = xtsp[b*3072 + k];
  __syncthreads();
  if (t < 32){
    float s = 0.f;
    for (int c = 0; c < 96; ++c){ float v = X[t*96+c]; s += v*v; }
    x2l[t] = s;
  }
  __syncthreads();
  if (t < 32){
    float dot = 0.f;
    for (int c = 0; c < 96; ++c) dot += X[i*96+c]*X[t*96+c];
    dd[t] = x2l[i] - 2.f*dot + x2l[t];
  }
  __syncthreads();
  if (t == 0){
    int s0 = -1, s1 = -1;
    for (int j = 0; j < 32; ++j){
      float dj = dd[j];
      if (s0 < 0 || dj < dd[s0]){ s1 = s0; s0 = j; }
      else if (s1 < 0 || dj < dd[s1]){ s1 = j; }
    }
    nb[0] = s0; nb[1] = s1;
  }
  __syncthreads();
  __shared__ __align__(16) float E[192];
  __shared__ __align__(16) float H1[156];
  float acc = -3.4e38f;
  for (int n = 0; n < 2; ++n){
    int j = nb[n];
    if (t < 96){ E[t] = X[j*96+t] - X[i*96+t]; E[96+t] = X[i*96+t]; }
    __syncthreads();
    if (t < 156){
      float h = bb1[t];
      const float* wr = W1 + t*192;
      for (int k = 0; k < 192; ++k) h += E[k]*wr[k];
      H1[t] = leaky(h);
    }
    __syncthreads();
    if (t < 128){
      float h = bb2[t];
      const float* wr = W2 + t*156;
      for (int m = 0; m < 156; ++m) h += H1[m]*wr[m];
      acc = fmaxf(acc, leaky(h));
    }
    __syncthreads();
  }
  if (t < 128) outp[(b*128 + t)*32 + i] = acc;
}

// ---------------- kNN pass A: MFMA scores -> per-query histogram -> threshold bin ----------------
__global__ __launch_bounds__(256) void k_histA(const unsigned short* __restrict__ xtb,
                                               const float* __restrict__ x2,
                                               float* __restrict__ thrF){
  __shared__ unsigned hist[8192];              // 64 queries x 128 words (2 bins/word)
  __shared__ __align__(16) unsigned short Bb[6144];   // 64 cands x 96 bf16
  __shared__ float x2t[64];
  int b = blockIdx.x >> 7, q0 = (blockIdx.x & 127) << 6;
  int tid = threadIdx.x, w = tid >> 6, lane = tid & 63;
  int nl = lane & 15, quad = lane >> 4;
  for (int i = tid; i < 8192; i += 256) hist[i] = 0u;
  // A-frags: wave w holds queries q0+16w .. +15; lane row m = lane&15, k = quad*8..+7
  s16x8 af0, af1, af2;
  {
    const unsigned short* arow = xtb + (size_t)(b*8192 + q0 + 16*w + nl)*96;
    af0 = *(const s16x8*)(arow + quad*8);
    af1 = *(const s16x8*)(arow + 32 + quad*8);
    af2 = *(const s16x8*)(arow + 64 + quad*8);
  }
  float x2q[4];
  #pragma unroll
  for (int r = 0; r < 4; ++r) x2q[r] = x2[b*8192 + q0 + 16*w + quad*4 + r];
  const unsigned short* cb = xtb + (size_t)b*8192*96;
  for (int ct = 0; ct < 128; ++ct){
    __syncthreads();
    {
      const s16x8* src = (const s16x8*)(cb + (size_t)ct*6144);
      s16x8* dst = (s16x8*)Bb;
      dst[tid] = src[tid]; dst[tid+256] = src[tid+256]; dst[tid+512] = src[tid+512];
      if (tid < 64) x2t[tid] = x2[b*8192 + ct*64 + tid];
    }
    __syncthreads();
    #pragma unroll
    for (int sub = 0; sub < 4; ++sub){
      f32x4 acc = {0.f, 0.f, 0.f, 0.f};
      const unsigned short* brow = Bb + (sub*16 + nl)*96 + quad*8;
      s16x8 b0 = *(const s16x8*)(brow);
      s16x8 b1 = *(const s16x8*)(brow + 32);
      s16x8 b2 = *(const s16x8*)(brow + 64);
      acc = __builtin_amdgcn_mfma_f32_16x16x32_bf16(af0, b0, acc, 0, 0, 0);
      acc = __builtin_amdgcn_mfma_f32_16x16x32_bf16(af1, b1, acc, 0, 0, 0);
      acc = __builtin_amdgcn_mfma_f32_16x16x32_bf16(af2, b2, acc, 0, 0, 0);
      float x2c = x2t[sub*16 + nl];
      #pragma unroll
      for (int r = 0; r < 4; ++r){
        int bin = score_bin(acc[r], x2c, x2q[r]);
        int ql = 16*w + quad*4 + r;
        unsigned word = (unsigned)((ql << 7) | ((bin >> 1) ^ ((ql & 3) << 3)));
        atomicAdd(&hist[word], (bin & 1) ? 0x10000u : 1u);
      }
    }
  }
  __syncthreads();
  if (tid < 64){
    int ql = tid; unsigned cum = 0; int tb = 1;
    for (int bin = 255; bin >= 1; --bin){
      unsigned word = (unsigned)((ql << 7) | ((bin >> 1) ^ ((ql & 3) << 3)));
      unsigned c = (hist[word] >> ((bin & 1)*16)) & 0xFFFFu;
      cum += c;
      if (cum >= 64u){ tb = bin; break; }
    }
    thrF[b*8192 + q0 + ql] = (float)tb;
  }
}

// ---------------- kNN pass B: collect bin>=tb, fp64 rerank -> exact top-50 set ----------------
__global__ __launch_bounds__(256) void k_collectB(const unsigned short* __restrict__ xtb,
                                                  const float* __restrict__ x2,
                                                  const float* __restrict__ thrF,
                                                  const float* __restrict__ xt,
                                                  int* __restrict__ i50){
  __shared__ __align__(16) unsigned short Bb[6144];
  __shared__ float x2t[64];
  __shared__ unsigned short idxL[64][256];
  __shared__ unsigned cnt[64];
  __shared__ unsigned ocnt[64];
  int b = blockIdx.x >> 7, q0 = (blockIdx.x & 127) << 6;
  int tid = threadIdx.x, w = tid >> 6, lane = tid & 63;
  int nl = lane & 15, quad = lane >> 4;
  if (tid < 64){ cnt[tid] = 0u; ocnt[tid] = 0u; }
  s16x8 af0, af1, af2;
  {
    const unsigned short* arow = xtb + (size_t)(b*8192 + q0 + 16*w + nl)*96;
    af0 = *(const s16x8*)(arow + quad*8);
    af1 = *(const s16x8*)(arow + 32 + quad*8);
    af2 = *(const s16x8*)(arow + 64 + quad*8);
  }
  float x2q[4]; int tbi[4];
  #pragma unroll
  for (int r = 0; r < 4; ++r){
    int q = b*8192 + q0 + 16*w + quad*4 + r;
    x2q[r] = x2[q]; tbi[r] = (int)thrF[q];
  }
  const unsigned short* cb = xtb + (size_t)b*8192*96;
  for (int ct = 0; ct < 128; ++ct){
    __syncthreads();
    {
      const s16x8* src = (const s16x8*)(cb + (size_t)ct*6144);
      s16x8* dst = (s16x8*)Bb;
      dst[tid] = src[tid]; dst[tid+256] = src[tid+256]; dst[tid+512] = src[tid+512];
      if (tid < 64) x2t[tid] = x2[b*8192 + ct*64 + tid];
    }
    __syncthreads();
    #pragma unroll
    for (int sub = 0; sub < 4; ++sub){
      f32x4 acc = {0.f, 0.f, 0.f, 0.f};
      const unsigned short* brow = Bb + (sub*16 + nl)*96 + quad*8;
      s16x8 b0 = *(const s16x8*)(brow);
      s16x8 b1 = *(const s16x8*)(brow + 32);
      s16x8 b2 = *(const s16x8*)(brow + 64);
      acc = __builtin_amdgcn_mfma_f32_16x16x32_bf16(af0, b0, acc, 0, 0, 0);
      acc = __builtin_amdgcn_mfma_f32_16x16x32_bf16(af1, b1, acc, 0, 0, 0);
      acc = __builtin_amdgcn_mfma_f32_16x16x32_bf16(af2, b2, acc, 0, 0, 0);
      float x2c = x2t[sub*16 + nl];
      int cand = ct*64 + sub*16 + nl;
      #pragma unroll
      for (int r = 0; r < 4; ++r){
        int bin = score_bin(acc[r], x2c, x2q[r]);
        if (bin >= tbi[r]){
          int ql = 16*w + quad*4 + r;
          unsigned pos = atomicAdd(&cnt[ql], 1u);
          if (pos < 256u) idxL[ql][pos] = (unsigned short)cand;
        }
      }
    }
  }
  __syncthreads();
  // fp64 rerank: wave w handles query ql = rep*4 + w
  for (int rep = 0; rep < 16; ++rep){
    int ql = rep*4 + w;
    int gq = b*8192 + q0 + ql;
    unsigned craw = cnt[ql];
    int cq = (int)(craw < 256u ? craw : 256u);
    const float* xq = xt + (size_t)gq*96;
    double x2qd = 0.0;
    #pragma unroll 8
    for (int c = 0; c < 96; ++c){ double v = (double)xq[c]; x2qd += v*v; }
    double dl[4]; int il[4]; bool alive[4];
    #pragma unroll
    for (int s = 0; s < 4; ++s){
      int k = s*64 + lane;
      alive[s] = (k < cq);
      il[s] = alive[s] ? (int)idxL[ql][k] : -1;
      dl[s] = 0.0;
    }
    #pragma unroll
    for (int s = 0; s < 4; ++s){
      if (alive[s]){
        const float* xc = xt + (size_t)(b*8192 + il[s])*96;
        double dot = 0.0, x2j = 0.0;
        #pragma unroll 8
        for (int c = 0; c < 96; ++c){
          double xv = (double)xc[c];
          dot += xv*(double)xq[c];
          x2j += xv*xv;
        }
        dl[s] = x2qd + x2j - 2.0*dot;     // exactly 0 for self
      }
    }
    int A = cq;
    while (A > 50){
      double wd = -1.0; int wi = -1; int ws_ = -1;
      #pragma unroll
      for (int s = 0; s < 4; ++s){
        if (alive[s] && (dl[s] > wd || (dl[s] == wd && il[s] > wi))){ wd = dl[s]; wi = il[s]; ws_ = s; }
      }
      double gd = wd; int gi = wi;
      #pragma unroll
      for (int off = 32; off > 0; off >>= 1){
        double od = __shfl_xor(gd, off);
        int    oi = __shfl_xor(gi, off);
        if (od > gd || (od == gd && oi > gi)){ gd = od; gi = oi; }
      }
      if (ws_ >= 0 && wi == gi && wd == gd) alive[ws_] = false;  // unique owner
      --A;
    }
    #pragma unroll
    for (int s = 0; s < 4; ++s){
      if (alive[s]){
        unsigned pos = atomicAdd(&ocnt[ql], 1u);
        i50[(size_t)gq*50 + pos] = il[s];
      }
    }
  }
}

// ---------------- EdgeConv factorization: g1, p1 ----------------
__global__ void k_g1p1(const float* __restrict__ xt, const float* __restrict__ W1,
                       const float* __restrict__ bb1,
                       float* __restrict__ g1, float* __restrict__ p1){
  __shared__ float xl[8*96];
  int p0 = blockIdx.x*8;
  int t = threadIdx.x;
  for (int k = t; k < 768; k += 256) xl[k] = xt[(size_t)p0*96 + k];
  __syncthreads();
  for (int oi = t; oi < 880; oi += 256){
    int pi = oi/110, m = oi - pi*110;
    const float* wr = W1 + m*192;
    float a = 0.f, c2 = 0.f;
    for (int c = 0; c < 96; ++c){ float xv = xl[pi*96+c]; a += wr[c]*xv; c2 += wr[96+c]*xv; }
    g1[(size_t)(p0+pi)*110 + m] = a;
    p1[(size_t)(p0+pi)*110 + m] = c2 - a + bb1[m];
  }
}

// ---------------- dense EdgeConv W2 GEMM + max over 50 neighbors ----------------
__global__ __launch_bounds__(64) void k_econv(const float* __restrict__ g1,
                                              const float* __restrict__ p1,
                                              const int* __restrict__ idx50,
                                              const float* __restrict__ W2,
                                              const float* __restrict__ bb2,
                                              float* __restrict__ cin){
  int gq = blockIdx.x;
  int b = gq >> 13;
  int l = threadIdx.x;
  float w2[110];
  #pragma unroll
  for (int m = 0; m < 110; ++m) w2[m] = W2[l*110 + m];
  float pA = p1[(size_t)gq*110 + l];
  float pB = (l < 46) ? p1[(size_t)gq*110 + 64 + l] : 0.f;
  float bias = bb2[l];
  __shared__ __align__(16) float tb[112];
  float omax = -3.4e38f;
  for (int n = 0; n < 50; ++n){
    int j = idx50[(size_t)gq*50 + n];
    size_t gj = (size_t)(b*8192 + j)*110;
    float gA = g1[gj + l];
    float gB = (l < 46) ? g1[gj + 64 + l] : 0.f;
    __syncthreads();
    tb[l] = leaky(gA + pA);
    if (l < 46) tb[64 + l] = leaky(gB + pB);
    __syncthreads();
    float acc = bias;
    #pragma unroll
    for (int m = 0; m < 110; ++m) acc += w2[m]*tb[m];
    omax = fmaxf(omax, leaky(acc));
  }
  cin[(size_t)gq*64 + l] = omax;
}

// ---------------- downsample conv (1,3) stride (1,2) pad (0,1) ----------------
__global__ void k_down(const float* __restrict__ cin, const float* __restrict__ Wd,
                       const float* __restrict__ bias, float* __restrict__ outp){
  int b = blockIdx.x >> 6; int r = blockIdx.x & 63;
  int s = r >> 1; int ph = r & 1;
  int t = threadIdx.x;
  __shared__ float L[130*65];
  for (int k = t; k < 130*64; k += 256){
    int rr = k >> 6, i = k & 63;
    int pp = ph*128 - 1 + rr;
    float v = 0.f;
    if (pp >= 0 && pp < 256) v = cin[(size_t)((b*8192 + s*256 + pp))*64 + i];
    L[rr*65 + i] = v;
  }
  __syncthreads();
  for (int ow = t; ow < 4096; ow += 256){
    int o = ow >> 6, wl = ow & 63;
    int w = ph*64 + wl;
    float acc = bias[o];
    #pragma unroll
    for (int tt = 0; tt < 3; ++tt){
      int rr = 2*wl + tt;
      const float* wr = Wd + o*192 + tt;
      for (int i = 0; i < 64; ++i) acc += L[rr*65 + i]*wr[i*3];
    }
    outp[16384 + ((size_t)((b*64 + o)*32 + s))*128 + w] = leaky(acc);
  }
}

extern "C" void kernel_launch(void* const* d_in, const int* in_sizes, int n_in,
                              void* d_out, int out_size, void* d_ws, size_t ws_size,
                              hipStream_t stream){
  (void)in_sizes; (void)n_in; (void)out_size; (void)ws_size;
  const float* sparse = (const float*)d_in[0];
  const float* dense  = (const float*)d_in[1];
  const float* spW1   = (const float*)d_in[2];
  const float* spb1   = (const float*)d_in[3];
  const float* spW2   = (const float*)d_in[4];
  const float* spb2   = (const float*)d_in[5];
  const float* dnW1   = (const float*)d_in[6];
  const float* dnb1   = (const float*)d_in[7];
  const float* dnW2   = (const float*)d_in[8];
  const float* dnb2   = (const float*)d_in[9];
  const float* dsW    = (const float*)d_in[10];
  const float* dsb    = (const float*)d_in[11];
  float* out = (float*)d_out;

  float* w    = (float*)d_ws;                  // 62.96 MB
  float* xt   = w;                             // 3,145,728
  float* x2   = w + 3145728;                   //    32,768
  float* g1   = w + 3178496;                   // 3,604,480
  float* p1   = w + 6782976;                   // 3,604,480
  int*   i50  = (int*)(w + 10387456);          // 1,638,400
  float* cin  = w + 12025856;                  // 2,097,152
  float* xtsp = w + 14123008;                  //    12,288
  unsigned short* xtb = (unsigned short*)(w + 14135296);  // 3,145,728 bf16
  float* thrF = w + 15708160;                  //    32,768

  k_build_xt    <<<12288, 256, 0, stream>>>(dense, sparse, xt, xtb);
  k_x2          <<<128,   256, 0, stream>>>(xt, x2);
  k_sparse_union<<<128,   256, 0, stream>>>(sparse, dense, xtsp);
  k_sparse_gcn  <<<128,   192, 0, stream>>>(xtsp, spW1, spb1, spW2, spb2, out);
  k_histA       <<<512,   256, 0, stream>>>(xtb, x2, thrF);
  k_collectB    <<<512,   256, 0, stream>>>(xtb, x2, thrF, xt, i50);
  k_g1p1        <<<4096,  256, 0, stream>>>(xt, dnW1, dnb1, g1, p1);
  k_econv       <<<32768,  64, 0, stream>>>(g1, p1, i50, dnW2, dnb2, cin);
  k_down        <<<256,   256, 0, stream>>>(cin, dsW, dsb, out);
}

// Round 3
// 2120.897 us; speedup vs baseline: 2.7690x; 1.1154x over previous
//
#include <hip/hip_runtime.h>

// SDGraphUNet on MI355X — round 2: fused single-launch kNN.
//   phase 1: mates-only MFMA (4 tiles) -> atomic-free per-query u8 histograms -> rank-64 bin
//   phase 2: full MFMA scan (128 tiles), collect bin >= tb (bit-identical scores)
//   phase 3: exact fp32 rerank (LDS-staged, coalesced) -> exact top-50 set
//
// ws (floats): xt 3145728 | x2 32768 | g1 3604480 | p1 3604480 | i50 1638400(int)
//   | cin 2097152 | xtsp 12288 | xtb 1572864 (bf16 x 3145728)  total 15,708,160 = 62.8 MB

#define LEAKK 0.2f

typedef short s16x8 __attribute__((ext_vector_type(8)));
typedef float f32x4 __attribute__((ext_vector_type(4)));

__device__ __forceinline__ float leaky(float x){ return x > 0.f ? x : LEAKK*x; }

// shared by phase 1 & 2 -> bit-identical binning. bin in [124,255]; 255 ~ d=0.
__device__ __forceinline__ int score_bin(float acc, float x2c, float x2q){
  float s2 = __builtin_fmaf(2.f, acc, -x2c);
  float u  = (s2 - x2q) + 256.f;               // 256 - d_approx
  u = fminf(fmaxf(u, 124.f), 255.f);
  return (int)u;
}

// ---------------- build dense union features (fp32 + bf16) ----------------
__global__ void k_build_xt(const float* __restrict__ dense, const float* __restrict__ sparse,
                           float* __restrict__ xt, unsigned short* __restrict__ xtb){
  int t = blockIdx.x*256 + threadIdx.x;       // < 4*8192*96
  int c = t % 96;
  int rest = t / 96;
  int p = rest & 8191;
  int b = rest >> 13;
  int s = p >> 8, pp = p & 255;
  float v;
  if (c < 32) v = dense[(((b*32 + c)*32 + s) << 8) + pp];
  else        v = sparse[(b*64 + (c - 32))*32 + s];
  xt[t] = v;
  unsigned bits = __float_as_uint(v);
  unsigned r = (bits + 0x7FFFu + ((bits >> 16) & 1u)) >> 16;   // RNE to bf16
  xtb[t] = (unsigned short)r;
}

__global__ void k_x2(const float* __restrict__ xt, float* __restrict__ x2){
  int p = blockIdx.x*256 + threadIdx.x;       // < 32768
  const float4* r = (const float4*)(xt + (size_t)p*96);
  float a0=0.f, a1=0.f;
  #pragma unroll
  for (int k = 0; k < 24; k += 2){
    float4 v = r[k]; float4 u = r[k+1];
    a0 += v.x*v.x + v.y*v.y + v.z*v.z + v.w*v.w;
    a1 += u.x*u.x + u.y*u.y + u.z*u.z + u.w*u.w;
  }
  x2[p] = a0 + a1;
}

// ---------------- sparse union (max over points + concat) ----------------
__global__ void k_sparse_union(const float* __restrict__ sp, const float* __restrict__ dn,
                               float* __restrict__ xtsp){
  int b = blockIdx.x >> 5, i = blockIdx.x & 31;
  int w = threadIdx.x >> 6, l = threadIdx.x & 63;
  if (w == 0) xtsp[(b*32 + i)*96 + l] = sp[(b*64 + l)*32 + i];
  for (int c = w; c < 32; c += 4){
    const float* row = dn + (((size_t)(b*32 + c)*32 + i) << 8);
    float v = fmaxf(fmaxf(row[l], row[l+64]), fmaxf(row[l+128], row[l+192]));
    for (int off = 32; off > 0; off >>= 1) v = fmaxf(v, __shfl_down(v, off));
    if (l == 0) xtsp[(b*32 + i)*96 + 64 + c] = v;
  }
}

// ---------------- sparse GCN (k=2 over 32 strokes) ----------------
__global__ void k_sparse_gcn(const float* __restrict__ xtsp,
                             const float* __restrict__ W1, const float* __restrict__ bb1,
                             const float* __restrict__ W2, const float* __restrict__ bb2,
                             float* __restrict__ outp){
  int b = blockIdx.x >> 5, i = blockIdx.x & 31, t = threadIdx.x;
  __shared__ float X[32*96];
  __shared__ float x2l[32], dd[32];
  __shared__ int nb[2];
  for (int k = t; k < 3072; k += 192) X[k] = xtsp[b*3072 + k];
  __syncthreads();
  if (t < 32){
    float s = 0.f;
    for (int c = 0; c < 96; ++c){ float v = X[t*96+c]; s += v*v; }
    x2l[t] = s;
  }
  __syncthreads();
  if (t < 32){
    float dot = 0.f;
    for (int c = 0; c < 96; ++c) dot += X[i*96+c]*X[t*96+c];
    dd[t] = x2l[i] - 2.f*dot + x2l[t];
  }
  __syncthreads();
  if (t == 0){
    int s0 = -1, s1 = -1;
    for (int j = 0; j < 32; ++j){
      float dj = dd[j];
      if (s0 < 0 || dj < dd[s0]){ s1 = s0; s0 = j; }
      else if (s1 < 0 || dj < dd[s1]){ s1 = j; }
    }
    nb[0] = s0; nb[1] = s1;
  }
  __syncthreads();
  __shared__ __align__(16) float E[192];
  __shared__ __align__(16) float H1[156];
  float acc = -3.4e38f;
  for (int n = 0; n < 2; ++n){
    int j = nb[n];
    if (t < 96){ E[t] = X[j*96+t] - X[i*96+t]; E[96+t] = X[i*96+t]; }
    __syncthreads();
    if (t < 156){
      float h = bb1[t];
      const float* wr = W1 + t*192;
      for (int k = 0; k < 192; ++k) h += E[k]*wr[k];
      H1[t] = leaky(h);
    }
    __syncthreads();
    if (t < 128){
      float h = bb2[t];
      const float* wr = W2 + t*156;
      for (int m = 0; m < 156; ++m) h += H1[m]*wr[m];
      acc = fmaxf(acc, leaky(h));
    }
    __syncthreads();
  }
  if (t < 128) outp[(b*128 + t)*32 + i] = acc;
}

// ---- one GEMM tile: stage 64 cands, MFMA, write packed bins to binT ----
// (called from phase 1 and phase 2 -> identical arithmetic -> identical bins)
__device__ __forceinline__ void knn_tile(int ct, const unsigned short* cb,
                                         const float* x2b,
                                         short* Bb, unsigned char* binT, float* x2t,
                                         int tid, int w, int nl, int quad,
                                         const s16x8& af0, const s16x8& af1, const s16x8& af2,
                                         const float* x2q){
  { const s16x8* src = (const s16x8*)(cb + (size_t)ct*6144);
    s16x8* dst = (s16x8*)Bb;
    dst[tid] = src[tid]; dst[tid+256] = src[tid+256]; dst[tid+512] = src[tid+512];
    if (tid < 64) x2t[tid] = x2b[ct*64 + tid]; }
  __syncthreads();
  #pragma unroll
  for (int sub = 0; sub < 4; ++sub){
    f32x4 acc = {0.f, 0.f, 0.f, 0.f};
    const unsigned short* brow = (const unsigned short*)Bb + (sub*16 + nl)*96 + quad*8;
    s16x8 b0 = *(const s16x8*)(brow);
    s16x8 b1 = *(const s16x8*)(brow + 32);
    s16x8 b2 = *(const s16x8*)(brow + 64);
    acc = __builtin_amdgcn_mfma_f32_16x16x32_bf16(af0, b0, acc, 0, 0, 0);
    acc = __builtin_amdgcn_mfma_f32_16x16x32_bf16(af1, b1, acc, 0, 0, 0);
    acc = __builtin_amdgcn_mfma_f32_16x16x32_bf16(af2, b2, acc, 0, 0, 0);
    int c = sub*16 + nl;
    float x2c = x2t[c];
    unsigned pack = 0u;
    #pragma unroll
    for (int r = 0; r < 4; ++r)
      pack |= ((unsigned)score_bin(acc[r], x2c, x2q[r])) << (8*r);
    ((unsigned*)binT)[c*16 + 4*w + quad] = pack;   // bytes = queries 16w+quad*4 .. +3
  }
}

// ---------------- fused kNN: threshold -> collect -> fp32 rerank ----------------
__global__ __launch_bounds__(256) void k_knn(const unsigned short* __restrict__ xtb,
                                             const float* __restrict__ x2,
                                             const float* __restrict__ xt,
                                             int* __restrict__ i50){
  // [0,12288) Bb | [12288,16384) binT / ph3 distQ | [16384,17408) x2t,tbq,cnt,ocnt
  // [17408,50176) ph1 hist[132][128] u8 / ph2,3 idxL[64][256] u16
  // [50176,62592) ph3 rr: 4 waves x (8 rows x 97 f32)
  __shared__ __align__(16) char SM[62592];
  short* Bb = (short*)SM;
  unsigned char* binT = (unsigned char*)(SM + 12288);
  float* x2t = (float*)(SM + 16384);
  int* tbq = (int*)(SM + 16640);
  unsigned* cnt = (unsigned*)(SM + 16896);
  unsigned* ocnt = (unsigned*)(SM + 17152);
  unsigned char* hist = (unsigned char*)(SM + 17408);
  unsigned short* idxL = (unsigned short*)(SM + 17408);

  int b = blockIdx.x >> 7, q0 = (blockIdx.x & 127) << 6;
  int tid = threadIdx.x, w = tid >> 6, lane = tid & 63;
  int nl = lane & 15, quad = lane >> 4;

  for (int i = tid; i < 4224; i += 256) ((unsigned*)hist)[i] = 0u;   // 16896 B

  s16x8 af0, af1, af2;
  {
    const unsigned short* arow = xtb + (size_t)(b*8192 + q0 + 16*w + nl)*96;
    af0 = *(const s16x8*)(arow + quad*8);
    af1 = *(const s16x8*)(arow + 32 + quad*8);
    af2 = *(const s16x8*)(arow + 64 + quad*8);
  }
  float x2q[4];
  #pragma unroll
  for (int r = 0; r < 4; ++r) x2q[r] = x2[b*8192 + q0 + 16*w + quad*4 + r];

  const unsigned short* cb = xtb + (size_t)b*8192*96;
  const float* x2b = x2 + b*8192;
  int stroke = q0 >> 8;

  // ---- phase 1: mates-only histogram (4 tiles) ----
  for (int tt = 0; tt < 4; ++tt){
    __syncthreads();
    knn_tile(stroke*4 + tt, cb, x2b, Bb, binT, x2t, tid, w, nl, quad, af0, af1, af2, x2q);
    __syncthreads();
    if (tid < 128){
      int h = tid >> 6, q = tid & 63;
      #pragma unroll 8
      for (int i = 0; i < 32; ++i){
        int v = binT[(h*32 + i)*64 + q];
        unsigned char* hp = hist + (v - 124)*128 + (h << 6) + q;
        *hp = (unsigned char)(*hp + 1u);
      }
    }
  }
  __syncthreads();
  if (tid < 64){
    int q = tid; unsigned cum = 0u; int tb = 125;
    for (int bin = 255; bin >= 125; --bin){
      int bi = bin - 124;
      cum += (unsigned)hist[bi*128 + q] + (unsigned)hist[bi*128 + 64 + q];
      if (cum >= 64u){ tb = bin; break; }
    }
    tbq[q] = tb; cnt[q] = 0u; ocnt[q] = 0u;
  }
  __syncthreads();
  int mytb = tbq[lane];

  // ---- phase 2: full scan + collect ----
  for (int ct = 0; ct < 128; ++ct){
    __syncthreads();
    knn_tile(ct, cb, x2b, Bb, binT, x2t, tid, w, nl, quad, af0, af1, af2, x2q);
    __syncthreads();
    {
      int q = lane;
      #pragma unroll 4
      for (int i = 0; i < 16; ++i){
        int c = w*16 + i;
        int v = binT[c*64 + q];
        if (v >= mytb){
          unsigned pos = atomicAdd(&cnt[q], 1u);
          if (pos < 256u) idxL[q*256 + pos] = (unsigned short)(ct*64 + c);
        }
      }
    }
  }
  __syncthreads();

  // ---- phase 3: exact fp32 rerank, coalesced via LDS staging ----
  {
    float* distQ = (float*)(SM + 12288) + w*256;
    float* rr = (float*)(SM + 50176 + w*3104);   // [8 rows][97]
    int part = lane & 7, candl = lane >> 3;
    for (int rep = 0; rep < 16; ++rep){
      int q = w*16 + rep;
      int gq = b*8192 + q0 + q;
      unsigned craw = cnt[q];
      int cq = (int)(craw < 256u ? craw : 256u);
      float4 xq4[3];
      { const float4* xqp = (const float4*)(xt + (size_t)gq*96 + part*12);
        xq4[0] = xqp[0]; xq4[1] = xqp[1]; xq4[2] = xqp[2]; }
      int nch = (cq + 7) >> 3;
      for (int ch = 0; ch < nch; ++ch){
        #pragma unroll
        for (int i = 0; i < 3; ++i){
          int f = i*64 + lane;              // 0..191 float4 units (8 rows x 24)
          int r = f / 24, c4 = f - r*24;
          int k = ch*8 + r;
          int kk = k < cq ? k : 0;
          int j = idxL[q*256 + kk];
          float4 v = *(const float4*)(xt + (size_t)(b*8192 + j)*96 + c4*4);
          float* dst = rr + r*97 + c4*4;
          dst[0] = v.x; dst[1] = v.y; dst[2] = v.z; dst[3] = v.w;
        }
        float acc = 0.f;
        const float* rrr = rr + candl*97 + part*12;
        #pragma unroll
        for (int i = 0; i < 3; ++i){
          float4 xv = xq4[i];
          float d0 = rrr[i*4+0] - xv.x, d1 = rrr[i*4+1] - xv.y;
          float d2 = rrr[i*4+2] - xv.z, d3 = rrr[i*4+3] - xv.w;
          acc += d0*d0 + d1*d1 + d2*d2 + d3*d3;
        }
        acc += __shfl_xor(acc, 1);
        acc += __shfl_xor(acc, 2);
        acc += __shfl_xor(acc, 4);
        if (part == 0) distQ[ch*8 + candl] = acc;
      }
      // eliminate (cq-50) worst (largest d; tie -> larger index worse)
      float dsl[4]; int ils[4]; bool alive[4];
      #pragma unroll
      for (int s = 0; s < 4; ++s){
        int k = (s << 6) + lane;
        bool a = k < cq;
        alive[s] = a;
        ils[s] = a ? (int)idxL[q*256 + k] : -1;
        dsl[s] = a ? distQ[k] : -1.f;
      }
      int A = cq;
      while (A > 50){
        float wd = -1.f; int wi = -1; int wsl = -1;
        #pragma unroll
        for (int s = 0; s < 4; ++s)
          if (alive[s] && (dsl[s] > wd || (dsl[s] == wd && ils[s] > wi))){
            wd = dsl[s]; wi = ils[s]; wsl = s;
          }
        float gd = wd; int gi = wi;
        #pragma unroll
        for (int off = 32; off > 0; off >>= 1){
          float od = __shfl_xor(gd, off); int oi = __shfl_xor(gi, off);
          if (od > gd || (od == gd && oi > gi)){ gd = od; gi = oi; }
        }
        if (wsl >= 0 && wi == gi && wd == gd) alive[wsl] = false;
        --A;
      }
      #pragma unroll
      for (int s = 0; s < 4; ++s){
        if (alive[s]){
          unsigned pos = atomicAdd(&ocnt[q], 1u);
          if (pos < 50u) i50[(size_t)gq*50 + pos] = ils[s];
        }
      }
    }
  }
}

// ---------------- EdgeConv factorization: g1, p1 ----------------
__global__ void k_g1p1(const float* __restrict__ xt, const float* __restrict__ W1,
                       const float* __restrict__ bb1,
                       float* __restrict__ g1, float* __restrict__ p1){
  __shared__ float xl[8*96];
  int p0 = blockIdx.x*8;
  int t = threadIdx.x;
  for (int k = t; k < 768; k += 256) xl[k] = xt[(size_t)p0*96 + k];
  __syncthreads();
  for (int oi = t; oi < 880; oi += 256){
    int pi = oi/110, m = oi - pi*110;
    const float* wr = W1 + m*192;
    float a = 0.f, c2 = 0.f;
    for (int c = 0; c < 96; ++c){ float xv = xl[pi*96+c]; a += wr[c]*xv; c2 += wr[96+c]*xv; }
    g1[(size_t)(p0+pi)*110 + m] = a;
    p1[(size_t)(p0+pi)*110 + m] = c2 - a + bb1[m];
  }
}

// ---------------- dense EdgeConv W2 GEMM + max over 50 neighbors ----------------
__global__ __launch_bounds__(64) void k_econv(const float* __restrict__ g1,
                                              const float* __restrict__ p1,
                                              const int* __restrict__ idx50,
                                              const float* __restrict__ W2,
                                              const float* __restrict__ bb2,
                                              float* __restrict__ cin){
  int gq = blockIdx.x;
  int b = gq >> 13;
  int l = threadIdx.x;
  float w2[110];
  #pragma unroll
  for (int m = 0; m < 110; ++m) w2[m] = W2[l*110 + m];
  float pA = p1[(size_t)gq*110 + l];
  float pB = (l < 46) ? p1[(size_t)gq*110 + 64 + l] : 0.f;
  float bias = bb2[l];
  __shared__ __align__(16) float tb[112];
  float omax = -3.4e38f;
  for (int n = 0; n < 50; ++n){
    int j = idx50[(size_t)gq*50 + n];
    size_t gj = (size_t)(b*8192 + j)*110;
    float gA = g1[gj + l];
    float gB = (l < 46) ? g1[gj + 64 + l] : 0.f;
    __syncthreads();
    tb[l] = leaky(gA + pA);
    if (l < 46) tb[64 + l] = leaky(gB + pB);
    __syncthreads();
    float acc = bias;
    #pragma unroll
    for (int m = 0; m < 110; ++m) acc += w2[m]*tb[m];
    omax = fmaxf(omax, leaky(acc));
  }
  cin[(size_t)gq*64 + l] = omax;
}

// ---------------- downsample conv (1,3) stride (1,2) pad (0,1) ----------------
__global__ void k_down(const float* __restrict__ cin, const float* __restrict__ Wd,
                       const float* __restrict__ bias, float* __restrict__ outp){
  int b = blockIdx.x >> 6; int r = blockIdx.x & 63;
  int s = r >> 1; int ph = r & 1;
  int t = threadIdx.x;
  __shared__ float L[130*65];
  for (int k = t; k < 130*64; k += 256){
    int rr = k >> 6, i = k & 63;
    int pp = ph*128 - 1 + rr;
    float v = 0.f;
    if (pp >= 0 && pp < 256) v = cin[(size_t)((b*8192 + s*256 + pp))*64 + i];
    L[rr*65 + i] = v;
  }
  __syncthreads();
  for (int ow = t; ow < 4096; ow += 256){
    int o = ow >> 6, wl = ow & 63;
    int w = ph*64 + wl;
    float acc = bias[o];
    #pragma unroll
    for (int tt = 0; tt < 3; ++tt){
      int rr = 2*wl + tt;
      const float* wr = Wd + o*192 + tt;
      for (int i = 0; i < 64; ++i) acc += L[rr*65 + i]*wr[i*3];
    }
    outp[16384 + ((size_t)((b*64 + o)*32 + s))*128 + w] = leaky(acc);
  }
}

extern "C" void kernel_launch(void* const* d_in, const int* in_sizes, int n_in,
                              void* d_out, int out_size, void* d_ws, size_t ws_size,
                              hipStream_t stream){
  (void)in_sizes; (void)n_in; (void)out_size; (void)ws_size;
  const float* sparse = (const float*)d_in[0];
  const float* dense  = (const float*)d_in[1];
  const float* spW1   = (const float*)d_in[2];
  const float* spb1   = (const float*)d_in[3];
  const float* spW2   = (const float*)d_in[4];
  const float* spb2   = (const float*)d_in[5];
  const float* dnW1   = (const float*)d_in[6];
  const float* dnb1   = (const float*)d_in[7];
  const float* dnW2   = (const float*)d_in[8];
  const float* dnb2   = (const float*)d_in[9];
  const float* dsW    = (const float*)d_in[10];
  const float* dsb    = (const float*)d_in[11];
  float* out = (float*)d_out;

  float* w    = (float*)d_ws;                  // 62.8 MB
  float* xt   = w;
  float* x2   = w + 3145728;
  float* g1   = w + 3178496;
  float* p1   = w + 6782976;
  int*   i50  = (int*)(w + 10387456);
  float* cin  = w + 12025856;
  float* xtsp = w + 14123008;
  unsigned short* xtb = (unsigned short*)(w + 14135296);

  k_build_xt    <<<12288, 256, 0, stream>>>(dense, sparse, xt, xtb);
  k_x2          <<<128,   256, 0, stream>>>(xt, x2);
  k_sparse_union<<<128,   256, 0, stream>>>(sparse, dense, xtsp);
  k_sparse_gcn  <<<128,   192, 0, stream>>>(xtsp, spW1, spb1, spW2, spb2, out);
  k_knn         <<<512,   256, 0, stream>>>(xtb, x2, xt, i50);
  k_g1p1        <<<4096,  256, 0, stream>>>(xt, dnW1, dnb1, g1, p1);
  k_econv       <<<32768,  64, 0, stream>>>(g1, p1, i50, dnW2, dnb2, cin);
  k_down        <<<256,   256, 0, stream>>>(cin, dsW, dsb, out);
}

// Round 4
// 1622.159 us; speedup vs baseline: 3.6203x; 1.3075x over previous
//
#include <hip/hip_runtime.h>

// SDGraphUNet on MI355X — round 3.
//  k_knn: barrier-free fused kNN. Phase 1: mate scores in regs + bisection rank-64
//  threshold (shfl reductions, no LDS). Phase 2: full scan, bit-identical scores,
//  sparse collect. Phase 3: fp32 exact rerank (wave-private). B-frags from global.
//  k_econv: MFMA (hi/lo bf16 split, ~fp32 accuracy), W2 frags in LDS, 1 wave/query.
//  k_g1p1: W1 read once per block, stride-112 zero-padded outputs.
//  k_build_xt: LDS transpose (coalesced), fuses x2.
//
// ws (floats): xt 3145728 | x2 32768 | g1 3670016 | p1 3670016 | i50 1638400(int)
//   | cin 2097152 | xtsp 12288 | xtb 1572864   total 15,839,232 = 63.4 MB

#define LEAKK 0.2f

typedef short s16x8 __attribute__((ext_vector_type(8)));
typedef float f32x4 __attribute__((ext_vector_type(4)));

__device__ __forceinline__ float leaky(float x){ return x > 0.f ? x : LEAKK*x; }
__device__ __forceinline__ unsigned rne_bf16(float v){
  unsigned bits = __float_as_uint(v);
  return (bits + 0x7FFFu + ((bits >> 16) & 1u)) >> 16;
}

// ---------------- build dense union features (fp32 + bf16) + x2, via LDS transpose ----------------
__global__ __launch_bounds__(256) void k_build_xt(const float* __restrict__ dense,
                                                  const float* __restrict__ sparse,
                                                  float* __restrict__ xt,
                                                  unsigned short* __restrict__ xtb,
                                                  float* __restrict__ x2){
  __shared__ float D[32*257];
  __shared__ float sArr[64];
  int bs = blockIdx.x;              // 0..127 = b*32 + s
  int b = bs >> 5, s = bs & 31;
  int tid = threadIdx.x;
  if (tid < 64) sArr[tid] = sparse[(b*64 + tid)*32 + s];
  for (int i = tid; i < 8192; i += 256){
    int c = i >> 8, pp = i & 255;
    D[c*257 + pp] = dense[(((b*32 + c)*32 + s) << 8) + pp];
  }
  __syncthreads();
  float ss = 0.f;
  #pragma unroll
  for (int ch = 0; ch < 64; ++ch){ float v = sArr[ch]; ss = __builtin_fmaf(v, v, ss); }
  size_t base = ((size_t)b*8192 + s*256)*96;
  for (int i = tid; i < 24576; i += 256){
    int pp = i / 96, c = i - pp*96;
    float v = (c < 32) ? D[c*257 + pp] : sArr[c - 32];
    xt[base + i] = v;
    xtb[base + i] = (unsigned short)rne_bf16(v);
  }
  {
    int pp = tid;
    if (pp < 256){
      float a = ss;
      #pragma unroll
      for (int c = 0; c < 32; ++c){ float v = D[c*257 + pp]; a = __builtin_fmaf(v, v, a); }
      x2[b*8192 + s*256 + pp] = a;
    }
  }
}

// ---------------- sparse union (max over points + concat) ----------------
__global__ void k_sparse_union(const float* __restrict__ sp, const float* __restrict__ dn,
                               float* __restrict__ xtsp){
  int b = blockIdx.x >> 5, i = blockIdx.x & 31;
  int w = threadIdx.x >> 6, l = threadIdx.x & 63;
  if (w == 0) xtsp[(b*32 + i)*96 + l] = sp[(b*64 + l)*32 + i];
  for (int c = w; c < 32; c += 4){
    const float* row = dn + (((size_t)(b*32 + c)*32 + i) << 8);
    float v = fmaxf(fmaxf(row[l], row[l+64]), fmaxf(row[l+128], row[l+192]));
    for (int off = 32; off > 0; off >>= 1) v = fmaxf(v, __shfl_down(v, off));
    if (l == 0) xtsp[(b*32 + i)*96 + 64 + c] = v;
  }
}

// ---------------- sparse GCN (k=2 over 32 strokes) ----------------
__global__ void k_sparse_gcn(const float* __restrict__ xtsp,
                             const float* __restrict__ W1, const float* __restrict__ bb1,
                             const float* __restrict__ W2, const float* __restrict__ bb2,
                             float* __restrict__ outp){
  int b = blockIdx.x >> 5, i = blockIdx.x & 31, t = threadIdx.x;
  __shared__ float X[32*96];
  __shared__ float x2l[32], dd[32];
  __shared__ int nb[2];
  for (int k = t; k < 3072; k += 192) X[k] = xtsp[b*3072 + k];
  __syncthreads();
  if (t < 32){
    float s = 0.f;
    for (int c = 0; c < 96; ++c){ float v = X[t*96+c]; s += v*v; }
    x2l[t] = s;
  }
  __syncthreads();
  if (t < 32){
    float dot = 0.f;
    for (int c = 0; c < 96; ++c) dot += X[i*96+c]*X[t*96+c];
    dd[t] = x2l[i] - 2.f*dot + x2l[t];
  }
  __syncthreads();
  if (t == 0){
    int s0 = -1, s1 = -1;
    for (int j = 0; j < 32; ++j){
      float dj = dd[j];
      if (s0 < 0 || dj < dd[s0]){ s1 = s0; s0 = j; }
      else if (s1 < 0 || dj < dd[s1]){ s1 = j; }
    }
    nb[0] = s0; nb[1] = s1;
  }
  __syncthreads();
  __shared__ __align__(16) float E[192];
  __shared__ __align__(16) float H1[156];
  float acc = -3.4e38f;
  for (int n = 0; n < 2; ++n){
    int j = nb[n];
    if (t < 96){ E[t] = X[j*96+t] - X[i*96+t]; E[96+t] = X[i*96+t]; }
    __syncthreads();
    if (t < 156){
      float h = bb1[t];
      const float* wr = W1 + t*192;
      for (int k = 0; k < 192; ++k) h += E[k]*wr[k];
      H1[t] = leaky(h);
    }
    __syncthreads();
    if (t < 128){
      float h = bb2[t];
      const float* wr = W2 + t*156;
      for (int m = 0; m < 156; ++m) h += H1[m]*wr[m];
      acc = fmaxf(acc, leaky(h));
    }
    __syncthreads();
  }
  if (t < 128) outp[(b*128 + t)*32 + i] = acc;
}

// ---- 16 queries x 16 cands -> u = 256 - d_approx, lane holds 4 (rows quad*4+r) ----
// shared by phase 1 & 2 -> bit-identical scores
__device__ __forceinline__ f32x4 score16(s16x8 af0, s16x8 af1, s16x8 af2,
                                         const unsigned short* __restrict__ brow,
                                         float x2c, const float* x2q){
  s16x8 b0 = *(const s16x8*)(brow);
  s16x8 b1 = *(const s16x8*)(brow + 32);
  s16x8 b2 = *(const s16x8*)(brow + 64);
  f32x4 acc = {0.f,0.f,0.f,0.f};
  acc = __builtin_amdgcn_mfma_f32_16x16x32_bf16(af0, b0, acc, 0, 0, 0);
  acc = __builtin_amdgcn_mfma_f32_16x16x32_bf16(af1, b1, acc, 0, 0, 0);
  acc = __builtin_amdgcn_mfma_f32_16x16x32_bf16(af2, b2, acc, 0, 0, 0);
  f32x4 u;
  #pragma unroll
  for (int r = 0; r < 4; ++r)
    u[r] = (__builtin_fmaf(2.f, acc[r], -x2c) - x2q[r]) + 256.f;
  return u;
}

// ---------------- fused kNN: bisection threshold -> collect -> fp32 rerank ----------------
__global__ __launch_bounds__(256) void k_knn(const unsigned short* __restrict__ xtb,
                                             const float* __restrict__ x2,
                                             const float* __restrict__ xt,
                                             int* __restrict__ i50){
  // idxL u16[64][256]:0..32768 | cnt:32768 | ocnt:33024 | rr 4x776f:33280..45696 | distQ 4x256f:45696..49792
  __shared__ __align__(16) char SM[49792];
  unsigned short* idxL = (unsigned short*)SM;
  unsigned* cnt  = (unsigned*)(SM + 32768);
  unsigned* ocnt = (unsigned*)(SM + 33024);

  int b = blockIdx.x >> 7, q0 = (blockIdx.x & 127) << 6;
  int tid = threadIdx.x, w = tid >> 6, lane = tid & 63;
  int nl = lane & 15, quad = lane >> 4;

  s16x8 af0, af1, af2;
  {
    const unsigned short* arow = xtb + (size_t)(b*8192 + q0 + 16*w + nl)*96 + quad*8;
    af0 = *(const s16x8*)(arow);
    af1 = *(const s16x8*)(arow + 32);
    af2 = *(const s16x8*)(arow + 64);
  }
  float x2q[4];
  #pragma unroll
  for (int r = 0; r < 4; ++r) x2q[r] = x2[b*8192 + q0 + 16*w + quad*4 + r];

  const unsigned short* cb = xtb + (size_t)b*8192*96;
  const float* x2b = x2 + b*8192;

  if (quad == 0){ cnt[16*w + nl] = 0u; ocnt[16*w + nl] = 0u; }   // per-wave region

  // ---- phase 1: mate scores in regs + rank-64 threshold by bisection ----
  int stroke = q0 >> 8;
  f32x4 us[16];
  #pragma unroll
  for (int ss = 0; ss < 16; ++ss){
    int c0 = stroke*256 + ss*16;
    us[ss] = score16(af0, af1, af2, cb + (size_t)(c0 + nl)*96 + quad*8, x2b[c0 + nl], x2q);
  }
  float lo0=-4096.f, lo1=-4096.f, lo2=-4096.f, lo3=-4096.f;
  float hi0=257.f,   hi1=257.f,   hi2=257.f,   hi3=257.f;
  for (int it = 0; it < 13; ++it){
    float t0 = 0.5f*(lo0+hi0), t1 = 0.5f*(lo1+hi1), t2 = 0.5f*(lo2+hi2), t3 = 0.5f*(lo3+hi3);
    int c0=0, c1=0, c2=0, c3=0;
    #pragma unroll
    for (int ss = 0; ss < 16; ++ss){
      c0 += (us[ss][0] >= t0);
      c1 += (us[ss][1] >= t1);
      c2 += (us[ss][2] >= t2);
      c3 += (us[ss][3] >= t3);
    }
    unsigned p01 = (unsigned)c0 | ((unsigned)c1 << 16);
    unsigned p23 = (unsigned)c2 | ((unsigned)c3 << 16);
    #pragma unroll
    for (int off = 1; off <= 8; off <<= 1){
      p01 += (unsigned)__shfl_xor((int)p01, off);
      p23 += (unsigned)__shfl_xor((int)p23, off);
    }
    c0 = (int)(p01 & 0xFFFFu); c1 = (int)(p01 >> 16);
    c2 = (int)(p23 & 0xFFFFu); c3 = (int)(p23 >> 16);
    if (c0 >= 64) lo0 = t0; else hi0 = t0;
    if (c1 >= 64) lo1 = t1; else hi1 = t1;
    if (c2 >= 64) lo2 = t2; else hi2 = t2;
    if (c3 >= 64) lo3 = t3; else hi3 = t3;
  }
  float thr[4] = {lo0, lo1, lo2, lo3};

  // ---- phase 2: full scan (bit-identical scores) + sparse collect ----
  #pragma unroll 2
  for (int s = 0; s < 512; ++s){
    f32x4 u = score16(af0, af1, af2, cb + (size_t)(s*16 + nl)*96 + quad*8, x2b[s*16 + nl], x2q);
    int cand = s*16 + nl;
    #pragma unroll
    for (int r = 0; r < 4; ++r){
      if (u[r] >= thr[r]){
        int ql = 16*w + quad*4 + r;
        unsigned pos = atomicAdd(&cnt[ql], 1u);
        if (pos < 256u) idxL[ql*256 + pos] = (unsigned short)cand;
      }
    }
  }

  // ---- phase 3: exact fp32 rerank (wave-private, LDS-staged, coalesced) ----
  {
    float* rr = (float*)(SM + 33280) + w*776;       // [8 rows][97]
    float* distQ = (float*)(SM + 45696) + w*256;
    int part = lane & 7, candl = lane >> 3;
    for (int rep = 0; rep < 16; ++rep){
      int q = 16*w + rep;
      int gq = b*8192 + q0 + q;
      unsigned craw = cnt[q];
      int cq = (int)(craw < 256u ? craw : 256u);
      float4 xq4[3];
      { const float4* xqp = (const float4*)(xt + (size_t)gq*96 + part*12);
        xq4[0] = xqp[0]; xq4[1] = xqp[1]; xq4[2] = xqp[2]; }
      int nch = (cq + 7) >> 3;
      for (int ch = 0; ch < nch; ++ch){
        #pragma unroll
        for (int i = 0; i < 3; ++i){
          int f = i*64 + lane;
          int r = f / 24, c4 = f - r*24;
          int k = ch*8 + r;
          int kk = k < cq ? k : 0;
          int j = idxL[q*256 + kk];
          float4 v = *(const float4*)(xt + (size_t)(b*8192 + j)*96 + c4*4);
          float* dst = rr + r*97 + c4*4;
          dst[0] = v.x; dst[1] = v.y; dst[2] = v.z; dst[3] = v.w;
        }
        float acc = 0.f;
        const float* rrr = rr + candl*97 + part*12;
        #pragma unroll
        for (int i = 0; i < 3; ++i){
          float4 xv = xq4[i];
          float d0 = rrr[i*4+0] - xv.x, d1 = rrr[i*4+1] - xv.y;
          float d2 = rrr[i*4+2] - xv.z, d3 = rrr[i*4+3] - xv.w;
          acc += d0*d0 + d1*d1 + d2*d2 + d3*d3;
        }
        acc += __shfl_xor(acc, 1);
        acc += __shfl_xor(acc, 2);
        acc += __shfl_xor(acc, 4);
        if (part == 0) distQ[ch*8 + candl] = acc;
      }
      float dsl[4]; int ils[4]; bool alive[4];
      #pragma unroll
      for (int s2 = 0; s2 < 4; ++s2){
        int k = (s2 << 6) + lane;
        bool a = k < cq;
        alive[s2] = a;
        ils[s2] = a ? (int)idxL[q*256 + k] : -1;
        dsl[s2] = a ? distQ[k] : -1.f;
      }
      int A = cq;
      while (A > 50){
        float wd = -1.f; int wi = -1; int wsl = -1;
        #pragma unroll
        for (int s2 = 0; s2 < 4; ++s2)
          if (alive[s2] && (dsl[s2] > wd || (dsl[s2] == wd && ils[s2] > wi))){
            wd = dsl[s2]; wi = ils[s2]; wsl = s2;
          }
        float gd = wd; int gi = wi;
        #pragma unroll
        for (int off = 32; off > 0; off >>= 1){
          float od = __shfl_xor(gd, off); int oi = __shfl_xor(gi, off);
          if (od > gd || (od == gd && oi > gi)){ gd = od; gi = oi; }
        }
        if (wsl >= 0 && wi == gi && wd == gd) alive[wsl] = false;
        --A;
      }
      #pragma unroll
      for (int s2 = 0; s2 < 4; ++s2){
        if (alive[s2]){
          unsigned pos = atomicAdd(&ocnt[q], 1u);
          if (pos < 50u) i50[(size_t)gq*50 + pos] = ils[s2];
        }
      }
    }
  }
}

// ---------------- EdgeConv factorization: g1, p1 (stride 112, zero-padded) ----------------
__global__ __launch_bounds__(256) void k_g1p1(const float* __restrict__ xt,
                                              const float* __restrict__ W1,
                                              const float* __restrict__ bb1,
                                              float* __restrict__ g1,
                                              float* __restrict__ p1){
  __shared__ float xl[768];
  __shared__ float A[8*112];
  __shared__ float C2[8*112];
  int p0 = blockIdx.x*8;
  int t = threadIdx.x;
  for (int k = t; k < 768; k += 256) xl[k] = xt[(size_t)p0*96 + k];
  __syncthreads();
  if (t < 220){
    int m = t >> 1, h = t & 1;
    const float* wr = W1 + m*192 + h*96;
    float acc[8] = {0.f,0.f,0.f,0.f,0.f,0.f,0.f,0.f};
    for (int c = 0; c < 96; ++c){
      float wv = wr[c];
      #pragma unroll
      for (int pi = 0; pi < 8; ++pi)
        acc[pi] = __builtin_fmaf(wv, xl[pi*96 + c], acc[pi]);
    }
    float* dst = (h == 0) ? A : C2;
    #pragma unroll
    for (int pi = 0; pi < 8; ++pi) dst[pi*112 + m] = acc[pi];
  }
  __syncthreads();
  for (int i = t; i < 896; i += 256){
    int pi = i / 112, m = i - pi*112;
    bool vm = (m < 110);
    float a  = vm ? A[i]  : 0.f;
    float c2 = vm ? C2[i] : 0.f;
    g1[(size_t)(p0 + pi)*112 + m] = a;
    p1[(size_t)(p0 + pi)*112 + m] = vm ? (c2 - a + bb1[m]) : 0.f;
  }
}

// ---------------- dense EdgeConv: MFMA (hi/lo bf16 split) + max over 50 ----------------
__global__ __launch_bounds__(256) void k_econv(const float* __restrict__ g1,
                                               const float* __restrict__ p1,
                                               const int* __restrict__ i50,
                                               const float* __restrict__ W2,
                                               const float* __restrict__ bb2,
                                               float* __restrict__ cin){
  __shared__ __align__(16) unsigned short BH[2*64*136];   // W2 hi | lo, row stride 136
  unsigned short* bhi = BH;
  unsigned short* blo = BH + 64*136;
  int tid = threadIdx.x, w = tid >> 6, lane = tid & 63;
  int nl = lane & 15, quad = lane >> 4;
  for (int idx = tid; idx < 8192; idx += 256){
    int row = idx >> 7, k = idx & 127;
    float v = (k < 110) ? W2[row*110 + k] : 0.f;
    unsigned hb = rne_bf16(v);
    bhi[row*136 + k] = (unsigned short)hb;
    float hv = __uint_as_float(hb << 16);
    blo[row*136 + k] = (unsigned short)rne_bf16(v - hv);
  }
  __syncthreads();

  int gq = blockIdx.x*4 + w;
  int b = gq >> 13;
  const int* jrow = i50 + (size_t)gq*50;
  const float* pr = p1 + (size_t)gq*112;
  float m4[4] = {-3.4e38f, -3.4e38f, -3.4e38f, -3.4e38f};

  for (int rt = 0; rt < 4; ++rt){
    int e = rt*16 + nl;
    int j = jrow[e < 50 ? e : 49];
    const float* gr = g1 + (size_t)(b*8192 + j)*112;
    s16x8 ah[4], al[4];
    #pragma unroll
    for (int ks = 0; ks < 4; ++ks){
      if (ks == 3 && quad >= 2){
        #pragma unroll
        for (int i = 0; i < 8; ++i){ ah[3][i] = 0; al[3][i] = 0; }
      } else {
        int off = ks*32 + quad*8;
        float4 g0  = *(const float4*)(gr + off);
        float4 g1v = *(const float4*)(gr + off + 4);
        float4 p0  = *(const float4*)(pr + off);
        float4 p1v = *(const float4*)(pr + off + 4);
        float tv[8] = { leaky(g0.x+p0.x),  leaky(g0.y+p0.y),  leaky(g0.z+p0.z),  leaky(g0.w+p0.w),
                        leaky(g1v.x+p1v.x), leaky(g1v.y+p1v.y), leaky(g1v.z+p1v.z), leaky(g1v.w+p1v.w) };
        #pragma unroll
        for (int i = 0; i < 8; ++i){
          unsigned hb = rne_bf16(tv[i]);
          ah[ks][i] = (short)hb;
          float hv = __uint_as_float(hb << 16);
          al[ks][i] = (short)rne_bf16(tv[i] - hv);
        }
      }
    }
    f32x4 C[4] = {{0.f,0.f,0.f,0.f},{0.f,0.f,0.f,0.f},{0.f,0.f,0.f,0.f},{0.f,0.f,0.f,0.f}};
    #pragma unroll
    for (int ks = 0; ks < 4; ++ks){
      int ko = ks*64 + quad*16;                         // byte offset within row
      #pragma unroll
      for (int ct = 0; ct < 4; ++ct){
        const char* rp = (const char*)bhi + (ct*16 + nl)*272 + ko;
        s16x8 bh  = *(const s16x8*)(rp);
        s16x8 blv = *(const s16x8*)(rp + 64*136*2);
        C[ct] = __builtin_amdgcn_mfma_f32_16x16x32_bf16(ah[ks], bh,  C[ct], 0, 0, 0);
        C[ct] = __builtin_amdgcn_mfma_f32_16x16x32_bf16(al[ks], bh,  C[ct], 0, 0, 0);
        C[ct] = __builtin_amdgcn_mfma_f32_16x16x32_bf16(ah[ks], blv, C[ct], 0, 0, 0);
      }
    }
    if (rt < 3){
      #pragma unroll
      for (int ct = 0; ct < 4; ++ct)
        #pragma unroll
        for (int r = 0; r < 4; ++r) m4[ct] = fmaxf(m4[ct], C[ct][r]);
    } else {
      if (quad == 0){
        #pragma unroll
        for (int ct = 0; ct < 4; ++ct){
          m4[ct] = fmaxf(m4[ct], C[ct][0]);
          m4[ct] = fmaxf(m4[ct], C[ct][1]);
        }
      }
    }
  }
  #pragma unroll
  for (int ct = 0; ct < 4; ++ct){
    m4[ct] = fmaxf(m4[ct], __shfl_xor(m4[ct], 16));
    m4[ct] = fmaxf(m4[ct], __shfl_xor(m4[ct], 32));
  }
  if (quad == 0){
    #pragma unroll
    for (int ct = 0; ct < 4; ++ct){
      int o = ct*16 + nl;
      cin[(size_t)gq*64 + o] = leaky(m4[ct] + bb2[o]);
    }
  }
}

// ---------------- downsample conv (1,3) stride (1,2) pad (0,1) ----------------
__global__ void k_down(const float* __restrict__ cin, const float* __restrict__ Wd,
                       const float* __restrict__ bias, float* __restrict__ outp){
  int b = blockIdx.x >> 6; int r = blockIdx.x & 63;
  int s = r >> 1; int ph = r & 1;
  int t = threadIdx.x;
  __shared__ float L[130*65];
  for (int k = t; k < 130*64; k += 256){
    int rr = k >> 6, i = k & 63;
    int pp = ph*128 - 1 + rr;
    float v = 0.f;
    if (pp >= 0 && pp < 256) v = cin[(size_t)((b*8192 + s*256 + pp))*64 + i];
    L[rr*65 + i] = v;
  }
  __syncthreads();
  for (int ow = t; ow < 4096; ow += 256){
    int o = ow >> 6, wl = ow & 63;
    int w = ph*64 + wl;
    float acc = bias[o];
    #pragma unroll
    for (int tt = 0; tt < 3; ++tt){
      int rr = 2*wl + tt;
      const float* wr = Wd + o*192 + tt;
      for (int i = 0; i < 64; ++i) acc += L[rr*65 + i]*wr[i*3];
    }
    outp[16384 + ((size_t)((b*64 + o)*32 + s))*128 + w] = leaky(acc);
  }
}

extern "C" void kernel_launch(void* const* d_in, const int* in_sizes, int n_in,
                              void* d_out, int out_size, void* d_ws, size_t ws_size,
                              hipStream_t stream){
  (void)in_sizes; (void)n_in; (void)out_size; (void)ws_size;
  const float* sparse = (const float*)d_in[0];
  const float* dense  = (const float*)d_in[1];
  const float* spW1   = (const float*)d_in[2];
  const float* spb1   = (const float*)d_in[3];
  const float* spW2   = (const float*)d_in[4];
  const float* spb2   = (const float*)d_in[5];
  const float* dnW1   = (const float*)d_in[6];
  const float* dnb1   = (const float*)d_in[7];
  const float* dnW2   = (const float*)d_in[8];
  const float* dnb2   = (const float*)d_in[9];
  const float* dsW    = (const float*)d_in[10];
  const float* dsb    = (const float*)d_in[11];
  float* out = (float*)d_out;

  float* w    = (float*)d_ws;                  // 63.4 MB
  float* xt   = w;                             // 3,145,728
  float* x2   = w + 3145728;                   //    32,768
  float* g1   = w + 3178496;                   // 3,670,016 (stride 112)
  float* p1   = w + 6848512;                   // 3,670,016
  int*   i50  = (int*)(w + 10518528);          // 1,638,400
  float* cin  = w + 12156928;                  // 2,097,152
  float* xtsp = w + 14254080;                  //    12,288
  unsigned short* xtb = (unsigned short*)(w + 14266368);  // 3,145,728 u16

  k_build_xt    <<<128,  256, 0, stream>>>(dense, sparse, xt, xtb, x2);
  k_sparse_union<<<128,  256, 0, stream>>>(sparse, dense, xtsp);
  k_sparse_gcn  <<<128,  192, 0, stream>>>(xtsp, spW1, spb1, spW2, spb2, out);
  k_knn         <<<512,  256, 0, stream>>>(xtb, x2, xt, i50);
  k_g1p1        <<<4096, 256, 0, stream>>>(xt, dnW1, dnb1, g1, p1);
  k_econv       <<<8192, 256, 0, stream>>>(g1, p1, i50, dnW2, dnb2, cin);
  k_down        <<<256,  256, 0, stream>>>(cin, dsW, dsb, out);
}

// Round 5
// 1418.379 us; speedup vs baseline: 4.1405x; 1.1437x over previous
//
#include <hip/hip_runtime.h>

// SDGraphUNet on MI355X — round 4.
//  k_knn v2: each wave holds A-frags for ALL 64 block queries; candidate scan
//  range-split across waves (4x B-reuse, 4x fewer loads per MFMA). Bisection
//  thresholds shared via LDS (2 barriers total). Phase-3 fp32 rerank unchanged.
//  k_build_xt: 512 blocks. k_g1p1: float4 inner. k_econv: trunc-based hi/lo split.
//
// ws (floats): xt 3145728 | x2 32768 | g1 3670016 | p1 3670016 | i50 1638400(int)
//   | cin 2097152 | xtsp 12288 | xtb 1572864   total 15,839,232 = 63.4 MB

#define LEAKK 0.2f

typedef short s16x8 __attribute__((ext_vector_type(8)));
typedef float f32x4 __attribute__((ext_vector_type(4)));

__device__ __forceinline__ float leaky(float x){ return x > 0.f ? x : LEAKK*x; }
__device__ __forceinline__ unsigned rne_bf16(float v){
  unsigned bits = __float_as_uint(v);
  return (bits + 0x7FFFu + ((bits >> 16) & 1u)) >> 16;
}

// ---------------- build dense union features (fp32 + bf16) + x2 ----------------
__global__ __launch_bounds__(256) void k_build_xt(const float* __restrict__ dense,
                                                  const float* __restrict__ sparse,
                                                  float* __restrict__ xt,
                                                  unsigned short* __restrict__ xtb,
                                                  float* __restrict__ x2){
  __shared__ float D[32*65];          // 32 ch x 64 pp
  __shared__ float sArr[64];
  int blk = blockIdx.x;               // ((b*32+s)*4 + q4)
  int q4 = blk & 3, bs = blk >> 2, b = bs >> 5, s = bs & 31;
  int tid = threadIdx.x;
  if (tid < 64) sArr[tid] = sparse[(b*64 + tid)*32 + s];
  for (int i = tid; i < 2048; i += 256){
    int c = i >> 6, pp = i & 63;
    D[c*65 + pp] = dense[(((b*32 + c)*32 + s) << 8) + q4*64 + pp];
  }
  __syncthreads();
  float ss = 0.f;
  #pragma unroll
  for (int ch = 0; ch < 64; ++ch){ float v = sArr[ch]; ss = __builtin_fmaf(v, v, ss); }
  size_t base = ((size_t)b*8192 + s*256 + q4*64)*96;
  for (int i = tid; i < 6144; i += 256){
    int pp = i / 96, c = i - pp*96;
    float v = (c < 32) ? D[c*65 + pp] : sArr[c - 32];
    xt[base + i] = v;
    xtb[base + i] = (unsigned short)rne_bf16(v);
  }
  if (tid < 64){
    float a = ss;
    #pragma unroll
    for (int c = 0; c < 32; ++c){ float v = D[c*65 + tid]; a = __builtin_fmaf(v, v, a); }
    x2[b*8192 + s*256 + q4*64 + tid] = a;
  }
}

// ---------------- sparse union (max over points + concat) ----------------
__global__ void k_sparse_union(const float* __restrict__ sp, const float* __restrict__ dn,
                               float* __restrict__ xtsp){
  int b = blockIdx.x >> 5, i = blockIdx.x & 31;
  int w = threadIdx.x >> 6, l = threadIdx.x & 63;
  if (w == 0) xtsp[(b*32 + i)*96 + l] = sp[(b*64 + l)*32 + i];
  for (int c = w; c < 32; c += 4){
    const float* row = dn + (((size_t)(b*32 + c)*32 + i) << 8);
    float v = fmaxf(fmaxf(row[l], row[l+64]), fmaxf(row[l+128], row[l+192]));
    for (int off = 32; off > 0; off >>= 1) v = fmaxf(v, __shfl_down(v, off));
    if (l == 0) xtsp[(b*32 + i)*96 + 64 + c] = v;
  }
}

// ---------------- sparse GCN (k=2 over 32 strokes) ----------------
__global__ void k_sparse_gcn(const float* __restrict__ xtsp,
                             const float* __restrict__ W1, const float* __restrict__ bb1,
                             const float* __restrict__ W2, const float* __restrict__ bb2,
                             float* __restrict__ outp){
  int b = blockIdx.x >> 5, i = blockIdx.x & 31, t = threadIdx.x;
  __shared__ float X[32*96];
  __shared__ float x2l[32], dd[32];
  __shared__ int nb[2];
  for (int k = t; k < 3072; k += 192) X[k] = xtsp[b*3072 + k];
  __syncthreads();
  if (t < 32){
    float s = 0.f;
    for (int c = 0; c < 96; ++c){ float v = X[t*96+c]; s += v*v; }
    x2l[t] = s;
  }
  __syncthreads();
  if (t < 32){
    float dot = 0.f;
    for (int c = 0; c < 96; ++c) dot += X[i*96+c]*X[t*96+c];
    dd[t] = x2l[i] - 2.f*dot + x2l[t];
  }
  __syncthreads();
  if (t == 0){
    int s0 = -1, s1 = -1;
    for (int j = 0; j < 32; ++j){
      float dj = dd[j];
      if (s0 < 0 || dj < dd[s0]){ s1 = s0; s0 = j; }
      else if (s1 < 0 || dj < dd[s1]){ s1 = j; }
    }
    nb[0] = s0; nb[1] = s1;
  }
  __syncthreads();
  __shared__ __align__(16) float E[192];
  __shared__ __align__(16) float H1[156];
  float acc = -3.4e38f;
  for (int n = 0; n < 2; ++n){
    int j = nb[n];
    if (t < 96){ E[t] = X[j*96+t] - X[i*96+t]; E[96+t] = X[i*96+t]; }
    __syncthreads();
    if (t < 156){
      float h = bb1[t];
      const float* wr = W1 + t*192;
      for (int k = 0; k < 192; ++k) h += E[k]*wr[k];
      H1[t] = leaky(h);
    }
    __syncthreads();
    if (t < 128){
      float h = bb2[t];
      const float* wr = W2 + t*156;
      for (int m = 0; m < 156; ++m) h += H1[m]*wr[m];
      acc = fmaxf(acc, leaky(h));
    }
    __syncthreads();
  }
  if (t < 128) outp[(b*128 + t)*32 + i] = acc;
}

// ---- 16 queries x 16 cands -> u = 256 - d_approx; shared by both kNN phases ----
__device__ __forceinline__ f32x4 score16v(s16x8 a0, s16x8 a1, s16x8 a2,
                                          s16x8 b0, s16x8 b1, s16x8 b2,
                                          float x2c, const float* x2q){
  f32x4 acc = {0.f,0.f,0.f,0.f};
  acc = __builtin_amdgcn_mfma_f32_16x16x32_bf16(a0, b0, acc, 0, 0, 0);
  acc = __builtin_amdgcn_mfma_f32_16x16x32_bf16(a1, b1, acc, 0, 0, 0);
  acc = __builtin_amdgcn_mfma_f32_16x16x32_bf16(a2, b2, acc, 0, 0, 0);
  f32x4 u;
  #pragma unroll
  for (int r = 0; r < 4; ++r)
    u[r] = (__builtin_fmaf(2.f, acc[r], -x2c) - x2q[r]) + 256.f;
  return u;
}

// ---------------- fused kNN v2 ----------------
__global__ __launch_bounds__(256) void k_knn(const unsigned short* __restrict__ xtb,
                                             const float* __restrict__ x2,
                                             const float* __restrict__ xt,
                                             int* __restrict__ i50){
  // idxL u16[64][256]:0..32768 | cnt@32768 | ocnt@33024 | thrS@33280
  // rr 4x776f @33536..45952 | distQ 4x256f @45952..50048
  __shared__ __align__(16) char SM[50048];
  unsigned short* idxL = (unsigned short*)SM;
  unsigned* cnt  = (unsigned*)(SM + 32768);
  unsigned* ocnt = (unsigned*)(SM + 33024);
  float*    thrS = (float*)(SM + 33280);

  int b = blockIdx.x >> 7, q0 = (blockIdx.x & 127) << 6;
  int tid = threadIdx.x, w = tid >> 6, lane = tid & 63;
  int nl = lane & 15, quad = lane >> 4;

  if (tid < 64){ cnt[tid] = 0u; ocnt[tid] = 0u; }

  const unsigned short* cb = xtb + (size_t)b*8192*96;
  const float* x2b = x2 + b*8192;

  // A-frags for ALL 4 query groups (phase 2)
  s16x8 af[4][3];
  #pragma unroll
  for (int g = 0; g < 4; ++g){
    const unsigned short* arow = xtb + (size_t)(b*8192 + q0 + 16*g + nl)*96 + quad*8;
    af[g][0] = *(const s16x8*)(arow);
    af[g][1] = *(const s16x8*)(arow + 32);
    af[g][2] = *(const s16x8*)(arow + 64);
  }
  float x2qA[4][4];
  #pragma unroll
  for (int g = 0; g < 4; ++g)
    #pragma unroll
    for (int r = 0; r < 4; ++r)
      x2qA[g][r] = x2[b*8192 + q0 + 16*g + quad*4 + r];

  // ---- phase 1: wave w thresholds its own group (bisection on mate scores) ----
  {
    s16x8 aw0, aw1, aw2;
    const unsigned short* arow = xtb + (size_t)(b*8192 + q0 + 16*w + nl)*96 + quad*8;
    aw0 = *(const s16x8*)(arow);
    aw1 = *(const s16x8*)(arow + 32);
    aw2 = *(const s16x8*)(arow + 64);
    float x2qw[4];
    #pragma unroll
    for (int r = 0; r < 4; ++r) x2qw[r] = x2[b*8192 + q0 + 16*w + quad*4 + r];
    int stroke = q0 >> 8;
    f32x4 us[16];
    #pragma unroll
    for (int ss = 0; ss < 16; ++ss){
      int c0 = stroke*256 + ss*16;
      const unsigned short* brow = cb + (size_t)(c0 + nl)*96 + quad*8;
      s16x8 b0 = *(const s16x8*)(brow);
      s16x8 b1 = *(const s16x8*)(brow + 32);
      s16x8 b2 = *(const s16x8*)(brow + 64);
      us[ss] = score16v(aw0, aw1, aw2, b0, b1, b2, x2b[c0 + nl], x2qw);
    }
    float lo0=-4096.f, lo1=-4096.f, lo2=-4096.f, lo3=-4096.f;
    float hi0=257.f,   hi1=257.f,   hi2=257.f,   hi3=257.f;
    for (int it = 0; it < 13; ++it){
      float t0 = 0.5f*(lo0+hi0), t1 = 0.5f*(lo1+hi1), t2 = 0.5f*(lo2+hi2), t3 = 0.5f*(lo3+hi3);
      int c0=0, c1=0, c2=0, c3=0;
      #pragma unroll
      for (int ss = 0; ss < 16; ++ss){
        c0 += (us[ss][0] >= t0);
        c1 += (us[ss][1] >= t1);
        c2 += (us[ss][2] >= t2);
        c3 += (us[ss][3] >= t3);
      }
      unsigned p01 = (unsigned)c0 | ((unsigned)c1 << 16);
      unsigned p23 = (unsigned)c2 | ((unsigned)c3 << 16);
      #pragma unroll
      for (int off = 1; off <= 8; off <<= 1){
        p01 += (unsigned)__shfl_xor((int)p01, off);
        p23 += (unsigned)__shfl_xor((int)p23, off);
      }
      c0 = (int)(p01 & 0xFFFFu); c1 = (int)(p01 >> 16);
      c2 = (int)(p23 & 0xFFFFu); c3 = (int)(p23 >> 16);
      if (c0 >= 64) lo0 = t0; else hi0 = t0;
      if (c1 >= 64) lo1 = t1; else hi1 = t1;
      if (c2 >= 64) lo2 = t2; else hi2 = t2;
      if (c3 >= 64) lo3 = t3; else hi3 = t3;
    }
    if (nl == 0){
      thrS[16*w + quad*4 + 0] = lo0;
      thrS[16*w + quad*4 + 1] = lo1;
      thrS[16*w + quad*4 + 2] = lo2;
      thrS[16*w + quad*4 + 3] = lo3;
    }
  }
  __syncthreads();
  float thrA[4][4];
  #pragma unroll
  for (int g = 0; g < 4; ++g)
    #pragma unroll
    for (int r = 0; r < 4; ++r)
      thrA[g][r] = thrS[16*g + quad*4 + r];

  // ---- phase 2: wave w scans cands [w*2048, w*2048+2048) for ALL 64 queries ----
  int s0 = w*128;
  #pragma unroll 2
  for (int si = 0; si < 128; ++si){
    int s = s0 + si;
    const unsigned short* brow = cb + (size_t)(s*16 + nl)*96 + quad*8;
    s16x8 b0 = *(const s16x8*)(brow);
    s16x8 b1 = *(const s16x8*)(brow + 32);
    s16x8 b2 = *(const s16x8*)(brow + 64);
    float x2c = x2b[s*16 + nl];
    int cand = s*16 + nl;
    #pragma unroll
    for (int g = 0; g < 4; ++g){
      f32x4 u = score16v(af[g][0], af[g][1], af[g][2], b0, b1, b2, x2c, x2qA[g]);
      #pragma unroll
      for (int r = 0; r < 4; ++r){
        if (u[r] >= thrA[g][r]){
          int ql = 16*g + quad*4 + r;
          unsigned pos = atomicAdd(&cnt[ql], 1u);
          if (pos < 256u) idxL[ql*256 + pos] = (unsigned short)cand;
        }
      }
    }
  }
  __syncthreads();

  // ---- phase 3: exact fp32 rerank (wave-private, LDS-staged, coalesced) ----
  {
    float* rr = (float*)(SM + 33536) + w*776;       // [8 rows][97]
    float* distQ = (float*)(SM + 45952) + w*256;
    int part = lane & 7, candl = lane >> 3;
    for (int rep = 0; rep < 16; ++rep){
      int q = 16*w + rep;
      int gq = b*8192 + q0 + q;
      unsigned craw = cnt[q];
      int cq = (int)(craw < 256u ? craw : 256u);
      float4 xq4[3];
      { const float4* xqp = (const float4*)(xt + (size_t)gq*96 + part*12);
        xq4[0] = xqp[0]; xq4[1] = xqp[1]; xq4[2] = xqp[2]; }
      int nch = (cq + 7) >> 3;
      for (int ch = 0; ch < nch; ++ch){
        #pragma unroll
        for (int i = 0; i < 3; ++i){
          int f = i*64 + lane;
          int r = f / 24, c4 = f - r*24;
          int k = ch*8 + r;
          int kk = k < cq ? k : 0;
          int j = idxL[q*256 + kk];
          float4 v = *(const float4*)(xt + (size_t)(b*8192 + j)*96 + c4*4);
          float* dst = rr + r*97 + c4*4;
          dst[0] = v.x; dst[1] = v.y; dst[2] = v.z; dst[3] = v.w;
        }
        float acc = 0.f;
        const float* rrr = rr + candl*97 + part*12;
        #pragma unroll
        for (int i = 0; i < 3; ++i){
          float4 xv = xq4[i];
          float d0 = rrr[i*4+0] - xv.x, d1 = rrr[i*4+1] - xv.y;
          float d2 = rrr[i*4+2] - xv.z, d3 = rrr[i*4+3] - xv.w;
          acc += d0*d0 + d1*d1 + d2*d2 + d3*d3;
        }
        acc += __shfl_xor(acc, 1);
        acc += __shfl_xor(acc, 2);
        acc += __shfl_xor(acc, 4);
        if (part == 0) distQ[ch*8 + candl] = acc;
      }
      float dsl[4]; int ils[4]; bool alive[4];
      #pragma unroll
      for (int s2 = 0; s2 < 4; ++s2){
        int k = (s2 << 6) + lane;
        bool a = k < cq;
        alive[s2] = a;
        ils[s2] = a ? (int)idxL[q*256 + k] : -1;
        dsl[s2] = a ? distQ[k] : -1.f;
      }
      int A = cq;
      while (A > 50){
        float wd = -1.f; int wi = -1; int wsl = -1;
        #pragma unroll
        for (int s2 = 0; s2 < 4; ++s2)
          if (alive[s2] && (dsl[s2] > wd || (dsl[s2] == wd && ils[s2] > wi))){
            wd = dsl[s2]; wi = ils[s2]; wsl = s2;
          }
        float gd = wd; int gi = wi;
        #pragma unroll
        for (int off = 32; off > 0; off >>= 1){
          float od = __shfl_xor(gd, off); int oi = __shfl_xor(gi, off);
          if (od > gd || (od == gd && oi > gi)){ gd = od; gi = oi; }
        }
        if (wsl >= 0 && wi == gi && wd == gd) alive[wsl] = false;
        --A;
      }
      #pragma unroll
      for (int s2 = 0; s2 < 4; ++s2){
        if (alive[s2]){
          unsigned pos = atomicAdd(&ocnt[q], 1u);
          if (pos < 50u) i50[(size_t)gq*50 + pos] = ils[s2];
        }
      }
    }
  }
}

// ---------------- EdgeConv factorization: g1, p1 (stride 112, zero-padded) ----------------
__global__ __launch_bounds__(256) void k_g1p1(const float* __restrict__ xt,
                                              const float* __restrict__ W1,
                                              const float* __restrict__ bb1,
                                              float* __restrict__ g1,
                                              float* __restrict__ p1){
  __shared__ __align__(16) float xl[768];
  __shared__ float A[8*112];
  __shared__ float C2[8*112];
  int p0 = blockIdx.x*8;
  int t = threadIdx.x;
  for (int k = t; k < 768; k += 256) xl[k] = xt[(size_t)p0*96 + k];
  __syncthreads();
  if (t < 220){
    int m = t >> 1, h = t & 1;
    const float4* wr4 = (const float4*)(W1 + m*192 + h*96);
    float acc[8] = {0.f,0.f,0.f,0.f,0.f,0.f,0.f,0.f};
    #pragma unroll 6
    for (int c4 = 0; c4 < 24; ++c4){
      float4 wv = wr4[c4];
      #pragma unroll
      for (int pi = 0; pi < 8; ++pi){
        float4 xv = *(const float4*)(xl + pi*96 + c4*4);
        acc[pi] += wv.x*xv.x + wv.y*xv.y + wv.z*xv.z + wv.w*xv.w;
      }
    }
    float* dst = (h == 0) ? A : C2;
    #pragma unroll
    for (int pi = 0; pi < 8; ++pi) dst[pi*112 + m] = acc[pi];
  }
  __syncthreads();
  for (int i = t; i < 896; i += 256){
    int pi = i / 112, m = i - pi*112;
    bool vm = (m < 110);
    float a  = vm ? A[i]  : 0.f;
    float c2 = vm ? C2[i] : 0.f;
    g1[(size_t)(p0 + pi)*112 + m] = a;
    p1[(size_t)(p0 + pi)*112 + m] = vm ? (c2 - a + bb1[m]) : 0.f;
  }
}

// ---------------- dense EdgeConv: MFMA (hi/lo bf16 split) + max over 50 ----------------
__global__ __launch_bounds__(256) void k_econv(const float* __restrict__ g1,
                                               const float* __restrict__ p1,
                                               const int* __restrict__ i50,
                                               const float* __restrict__ W2,
                                               const float* __restrict__ bb2,
                                               float* __restrict__ cin){
  __shared__ __align__(16) unsigned short BH[2*64*136];   // W2 hi | lo, row stride 136
  unsigned short* bhi = BH;
  unsigned short* blo = BH + 64*136;
  int tid = threadIdx.x, w = tid >> 6, lane = tid & 63;
  int nl = lane & 15, quad = lane >> 4;
  for (int idx = tid; idx < 8192; idx += 256){
    int row = idx >> 7, k = idx & 127;
    float v = (k < 110) ? W2[row*110 + k] : 0.f;
    unsigned bits = __float_as_uint(v);
    bhi[row*136 + k] = (unsigned short)(bits >> 16);      // trunc hi
    float hv = __uint_as_float(bits & 0xFFFF0000u);
    blo[row*136 + k] = (unsigned short)rne_bf16(v - hv);
  }
  __syncthreads();

  int gq = blockIdx.x*4 + w;
  int b = gq >> 13;
  const int* jrow = i50 + (size_t)gq*50;
  const float* pr = p1 + (size_t)gq*112;
  float m4[4] = {-3.4e38f, -3.4e38f, -3.4e38f, -3.4e38f};

  for (int rt = 0; rt < 4; ++rt){
    int e = rt*16 + nl;
    int j = jrow[e < 50 ? e : 49];
    const float* gr = g1 + (size_t)(b*8192 + j)*112;
    s16x8 ah[4], al[4];
    #pragma unroll
    for (int ks = 0; ks < 4; ++ks){
      if (ks == 3 && quad >= 2){
        #pragma unroll
        for (int i = 0; i < 8; ++i){ ah[3][i] = 0; al[3][i] = 0; }
      } else {
        int off = ks*32 + quad*8;
        float4 g0  = *(const float4*)(gr + off);
        float4 g1v = *(const float4*)(gr + off + 4);
        float4 p0  = *(const float4*)(pr + off);
        float4 p1v = *(const float4*)(pr + off + 4);
        float tv[8] = { leaky(g0.x+p0.x),  leaky(g0.y+p0.y),  leaky(g0.z+p0.z),  leaky(g0.w+p0.w),
                        leaky(g1v.x+p1v.x), leaky(g1v.y+p1v.y), leaky(g1v.z+p1v.z), leaky(g1v.w+p1v.w) };
        #pragma unroll
        for (int i = 0; i < 8; ++i){
          unsigned bits = __float_as_uint(tv[i]);
          ah[ks][i] = (short)(bits >> 16);                // trunc hi
          float hv = __uint_as_float(bits & 0xFFFF0000u);
          al[ks][i] = (short)rne_bf16(tv[i] - hv);
        }
      }
    }
    f32x4 C[4] = {{0.f,0.f,0.f,0.f},{0.f,0.f,0.f,0.f},{0.f,0.f,0.f,0.f},{0.f,0.f,0.f,0.f}};
    #pragma unroll
    for (int ks = 0; ks < 4; ++ks){
      int ko = ks*64 + quad*16;                           // byte offset within row
      #pragma unroll
      for (int ct = 0; ct < 4; ++ct){
        const char* rp = (const char*)bhi + (ct*16 + nl)*272 + ko;
        s16x8 bh  = *(const s16x8*)(rp);
        s16x8 blv = *(const s16x8*)(rp + 64*136*2);
        C[ct] = __builtin_amdgcn_mfma_f32_16x16x32_bf16(ah[ks], bh,  C[ct], 0, 0, 0);
        C[ct] = __builtin_amdgcn_mfma_f32_16x16x32_bf16(al[ks], bh,  C[ct], 0, 0, 0);
        C[ct] = __builtin_amdgcn_mfma_f32_16x16x32_bf16(ah[ks], blv, C[ct], 0, 0, 0);
      }
    }
    if (rt < 3){
      #pragma unroll
      for (int ct = 0; ct < 4; ++ct)
        #pragma unroll
        for (int r = 0; r < 4; ++r) m4[ct] = fmaxf(m4[ct], C[ct][r]);
    } else {
      if (quad == 0){
        #pragma unroll
        for (int ct = 0; ct < 4; ++ct){
          m4[ct] = fmaxf(m4[ct], C[ct][0]);
          m4[ct] = fmaxf(m4[ct], C[ct][1]);
        }
      }
    }
  }
  #pragma unroll
  for (int ct = 0; ct < 4; ++ct){
    m4[ct] = fmaxf(m4[ct], __shfl_xor(m4[ct], 16));
    m4[ct] = fmaxf(m4[ct], __shfl_xor(m4[ct], 32));
  }
  if (quad == 0){
    #pragma unroll
    for (int ct = 0; ct < 4; ++ct){
      int o = ct*16 + nl;
      cin[(size_t)gq*64 + o] = leaky(m4[ct] + bb2[o]);
    }
  }
}

// ---------------- downsample conv (1,3) stride (1,2) pad (0,1) ----------------
__global__ void k_down(const float* __restrict__ cin, const float* __restrict__ Wd,
                       const float* __restrict__ bias, float* __restrict__ outp){
  int b = blockIdx.x >> 6; int r = blockIdx.x & 63;
  int s = r >> 1; int ph = r & 1;
  int t = threadIdx.x;
  __shared__ float L[130*65];
  for (int k = t; k < 130*64; k += 256){
    int rr = k >> 6, i = k & 63;
    int pp = ph*128 - 1 + rr;
    float v = 0.f;
    if (pp >= 0 && pp < 256) v = cin[(size_t)((b*8192 + s*256 + pp))*64 + i];
    L[rr*65 + i] = v;
  }
  __syncthreads();
  for (int ow = t; ow < 4096; ow += 256){
    int o = ow >> 6, wl = ow & 63;
    int w = ph*64 + wl;
    float acc = bias[o];
    #pragma unroll
    for (int tt = 0; tt < 3; ++tt){
      int rr = 2*wl + tt;
      const float* wr = Wd + o*192 + tt;
      for (int i = 0; i < 64; ++i) acc += L[rr*65 + i]*wr[i*3];
    }
    outp[16384 + ((size_t)((b*64 + o)*32 + s))*128 + w] = leaky(acc);
  }
}

extern "C" void kernel_launch(void* const* d_in, const int* in_sizes, int n_in,
                              void* d_out, int out_size, void* d_ws, size_t ws_size,
                              hipStream_t stream){
  (void)in_sizes; (void)n_in; (void)out_size; (void)ws_size;
  const float* sparse = (const float*)d_in[0];
  const float* dense  = (const float*)d_in[1];
  const float* spW1   = (const float*)d_in[2];
  const float* spb1   = (const float*)d_in[3];
  const float* spW2   = (const float*)d_in[4];
  const float* spb2   = (const float*)d_in[5];
  const float* dnW1   = (const float*)d_in[6];
  const float* dnb1   = (const float*)d_in[7];
  const float* dnW2   = (const float*)d_in[8];
  const float* dnb2   = (const float*)d_in[9];
  const float* dsW    = (const float*)d_in[10];
  const float* dsb    = (const float*)d_in[11];
  float* out = (float*)d_out;

  float* w    = (float*)d_ws;                  // 63.4 MB
  float* xt   = w;                             // 3,145,728
  float* x2   = w + 3145728;                   //    32,768
  float* g1   = w + 3178496;                   // 3,670,016 (stride 112)
  float* p1   = w + 6848512;                   // 3,670,016
  int*   i50  = (int*)(w + 10518528);          // 1,638,400
  float* cin  = w + 12156928;                  // 2,097,152
  float* xtsp = w + 14254080;                  //    12,288
  unsigned short* xtb = (unsigned short*)(w + 14266368);  // 3,145,728 u16

  k_build_xt    <<<512,  256, 0, stream>>>(dense, sparse, xt, xtb, x2);
  k_sparse_union<<<128,  256, 0, stream>>>(sparse, dense, xtsp);
  k_sparse_gcn  <<<128,  192, 0, stream>>>(xtsp, spW1, spb1, spW2, spb2, out);
  k_knn         <<<512,  256, 0, stream>>>(xtb, x2, xt, i50);
  k_g1p1        <<<4096, 256, 0, stream>>>(xt, dnW1, dnb1, g1, p1);
  k_econv       <<<8192, 256, 0, stream>>>(g1, p1, i50, dnW2, dnb2, cin);
  k_down        <<<256,  256, 0, stream>>>(cin, dsW, dsb, out);
}

// Round 6
// 882.668 us; speedup vs baseline: 6.6534x; 1.6069x over previous
//
#include <hip/hip_runtime.h>

// SDGraphUNet on MI355X — round 5.
//  k_prep : split W1cat(224x96)/W2 to bf16 hi/lo, transpose Wd -> wdt[3][64][64].
//  k_knn  : + depth-1 B prefetch (phase 2), chunk gather prefetch (phase 3),
//           XCD-aware block swizzle. Selection arithmetic bit-identical to R4.
//  k_g1p1 : MFMA hi/lo split GEMM, no LDS, no barriers.
//  k_econv: stages pre-split W2, p-row loads hoisted.
//  k_down : grid 1024, float4 LDS stride-68, wdt float4 weights.
//
// ws (floats): xt 3145728 | x2 32768 | g1 3670016 | p1 3670016 | i50 1638400(int)
//  | cin 2097152 | xtsp 12288 | xtb(u16) 1572864 | w1h 10752 | w1l 10752
//  | w2h 4096 | w2l 4096 | wdt 12288   total 15,881,216 floats = 63.5 MB

#define LEAKK 0.2f

typedef short s16x8 __attribute__((ext_vector_type(8)));
typedef float f32x4 __attribute__((ext_vector_type(4)));

__device__ __forceinline__ float leaky(float x){ return x > 0.f ? x : LEAKK*x; }
__device__ __forceinline__ unsigned rne_bf16(float v){
  unsigned bits = __float_as_uint(v);
  return (bits + 0x7FFFu + ((bits >> 16) & 1u)) >> 16;
}

// ---------------- prep: hi/lo splits + Wd transpose ----------------
__global__ __launch_bounds__(256) void k_prep(const float* __restrict__ W1,
                                              const float* __restrict__ W2,
                                              const float* __restrict__ Wd,
                                              unsigned short* __restrict__ w1h,
                                              unsigned short* __restrict__ w1l,
                                              unsigned short* __restrict__ w2h,
                                              unsigned short* __restrict__ w2l,
                                              float* __restrict__ wdt){
  int idx = blockIdx.x*256 + threadIdx.x;       // < 41984
  if (idx < 21504){
    int row = idx / 96, k = idx - row*96;
    float v = 0.f;
    if (row < 110) v = W1[row*192 + k];
    else if (row >= 112 && row < 222) v = W1[(row - 112)*192 + 96 + k];
    unsigned bits = __float_as_uint(v);
    w1h[idx] = (unsigned short)(bits >> 16);
    float hv = __uint_as_float(bits & 0xFFFF0000u);
    w1l[idx] = (unsigned short)rne_bf16(v - hv);
  } else if (idx < 29696){
    int j = idx - 21504;
    int row = j >> 7, k = j & 127;
    float v = (k < 110) ? W2[row*110 + k] : 0.f;
    unsigned bits = __float_as_uint(v);
    w2h[j] = (unsigned short)(bits >> 16);
    float hv = __uint_as_float(bits & 0xFFFF0000u);
    w2l[j] = (unsigned short)rne_bf16(v - hv);
  } else if (idx < 41984){
    int j = idx - 29696;                        // tt*4096 + o*64 + i
    int tt = j >> 12, rest = j & 4095, o = rest >> 6, i = rest & 63;
    wdt[j] = Wd[(o*64 + i)*3 + tt];
  }
}

// ---------------- build dense union features (fp32 + bf16) + x2 ----------------
__global__ __launch_bounds__(256) void k_build_xt(const float* __restrict__ dense,
                                                  const float* __restrict__ sparse,
                                                  float* __restrict__ xt,
                                                  unsigned short* __restrict__ xtb,
                                                  float* __restrict__ x2){
  __shared__ float D[32*65];
  __shared__ float sArr[64];
  int blk = blockIdx.x;               // ((b*32+s)*4 + q4)
  int q4 = blk & 3, bs = blk >> 2, b = bs >> 5, s = bs & 31;
  int tid = threadIdx.x;
  if (tid < 64) sArr[tid] = sparse[(b*64 + tid)*32 + s];
  for (int i = tid; i < 2048; i += 256){
    int c = i >> 6, pp = i & 63;
    D[c*65 + pp] = dense[(((b*32 + c)*32 + s) << 8) + q4*64 + pp];
  }
  __syncthreads();
  float ss = 0.f;
  #pragma unroll
  for (int ch = 0; ch < 64; ++ch){ float v = sArr[ch]; ss = __builtin_fmaf(v, v, ss); }
  size_t base = ((size_t)b*8192 + s*256 + q4*64)*96;
  for (int i = tid; i < 6144; i += 256){
    int pp = i / 96, c = i - pp*96;
    float v = (c < 32) ? D[c*65 + pp] : sArr[c - 32];
    xt[base + i] = v;
    xtb[base + i] = (unsigned short)rne_bf16(v);
  }
  if (tid < 64){
    float a = ss;
    #pragma unroll
    for (int c = 0; c < 32; ++c){ float v = D[c*65 + tid]; a = __builtin_fmaf(v, v, a); }
    x2[b*8192 + s*256 + q4*64 + tid] = a;
  }
}

// ---------------- sparse union (max over points + concat) ----------------
__global__ void k_sparse_union(const float* __restrict__ sp, const float* __restrict__ dn,
                               float* __restrict__ xtsp){
  int b = blockIdx.x >> 5, i = blockIdx.x & 31;
  int w = threadIdx.x >> 6, l = threadIdx.x & 63;
  if (w == 0) xtsp[(b*32 + i)*96 + l] = sp[(b*64 + l)*32 + i];
  for (int c = w; c < 32; c += 4){
    const float* row = dn + (((size_t)(b*32 + c)*32 + i) << 8);
    float v = fmaxf(fmaxf(row[l], row[l+64]), fmaxf(row[l+128], row[l+192]));
    for (int off = 32; off > 0; off >>= 1) v = fmaxf(v, __shfl_down(v, off));
    if (l == 0) xtsp[(b*32 + i)*96 + 64 + c] = v;
  }
}

// ---------------- sparse GCN (k=2 over 32 strokes) ----------------
__global__ void k_sparse_gcn(const float* __restrict__ xtsp,
                             const float* __restrict__ W1, const float* __restrict__ bb1,
                             const float* __restrict__ W2, const float* __restrict__ bb2,
                             float* __restrict__ outp){
  int b = blockIdx.x >> 5, i = blockIdx.x & 31, t = threadIdx.x;
  __shared__ float X[32*96];
  __shared__ float x2l[32], dd[32];
  __shared__ int nb[2];
  for (int k = t; k < 3072; k += 192) X[k] = xtsp[b*3072 + k];
  __syncthreads();
  if (t < 32){
    float s = 0.f;
    for (int c = 0; c < 96; ++c){ float v = X[t*96+c]; s += v*v; }
    x2l[t] = s;
  }
  __syncthreads();
  if (t < 32){
    float dot = 0.f;
    for (int c = 0; c < 96; ++c) dot += X[i*96+c]*X[t*96+c];
    dd[t] = x2l[i] - 2.f*dot + x2l[t];
  }
  __syncthreads();
  if (t == 0){
    int s0 = -1, s1 = -1;
    for (int j = 0; j < 32; ++j){
      float dj = dd[j];
      if (s0 < 0 || dj < dd[s0]){ s1 = s0; s0 = j; }
      else if (s1 < 0 || dj < dd[s1]){ s1 = j; }
    }
    nb[0] = s0; nb[1] = s1;
  }
  __syncthreads();
  __shared__ __align__(16) float E[192];
  __shared__ __align__(16) float H1[156];
  float acc = -3.4e38f;
  for (int n = 0; n < 2; ++n){
    int j = nb[n];
    if (t < 96){ E[t] = X[j*96+t] - X[i*96+t]; E[96+t] = X[i*96+t]; }
    __syncthreads();
    if (t < 156){
      float h = bb1[t];
      const float* wr = W1 + t*192;
      for (int k = 0; k < 192; ++k) h += E[k]*wr[k];
      H1[t] = leaky(h);
    }
    __syncthreads();
    if (t < 128){
      float h = bb2[t];
      const float* wr = W2 + t*156;
      for (int m = 0; m < 156; ++m) h += H1[m]*wr[m];
      acc = fmaxf(acc, leaky(h));
    }
    __syncthreads();
  }
  if (t < 128) outp[(b*128 + t)*32 + i] = acc;
}

// ---- 16 queries x 16 cands -> u = 256 - d_approx; shared by both kNN phases ----
__device__ __forceinline__ f32x4 score16v(s16x8 a0, s16x8 a1, s16x8 a2,
                                          s16x8 b0, s16x8 b1, s16x8 b2,
                                          float x2c, const float* x2q){
  f32x4 acc = {0.f,0.f,0.f,0.f};
  acc = __builtin_amdgcn_mfma_f32_16x16x32_bf16(a0, b0, acc, 0, 0, 0);
  acc = __builtin_amdgcn_mfma_f32_16x16x32_bf16(a1, b1, acc, 0, 0, 0);
  acc = __builtin_amdgcn_mfma_f32_16x16x32_bf16(a2, b2, acc, 0, 0, 0);
  f32x4 u;
  #pragma unroll
  for (int r = 0; r < 4; ++r)
    u[r] = (__builtin_fmaf(2.f, acc[r], -x2c) - x2q[r]) + 256.f;
  return u;
}

// ---------------- fused kNN v3 (prefetch-pipelined) ----------------
__global__ __launch_bounds__(256) void k_knn(const unsigned short* __restrict__ xtb,
                                             const float* __restrict__ x2,
                                             const float* __restrict__ xt,
                                             int* __restrict__ i50){
  __shared__ __align__(16) char SM[50048];
  unsigned short* idxL = (unsigned short*)SM;
  unsigned* cnt  = (unsigned*)(SM + 32768);
  unsigned* ocnt = (unsigned*)(SM + 33024);
  float*    thrS = (float*)(SM + 33280);

  // XCD-aware swizzle: batch pinned to an XCD pair (dispatch assumed round-robin)
  int b = (blockIdx.x & 7) >> 1;
  int chunkI = ((blockIdx.x >> 3) << 1) | (blockIdx.x & 1);
  int q0 = chunkI << 6;
  int tid = threadIdx.x, w = tid >> 6, lane = tid & 63;
  int nl = lane & 15, quad = lane >> 4;

  if (tid < 64){ cnt[tid] = 0u; ocnt[tid] = 0u; }

  const unsigned short* cb = xtb + (size_t)b*8192*96;
  const float* x2b = x2 + b*8192;

  // A-frags for ALL 4 query groups (phase 2)
  s16x8 af[4][3];
  #pragma unroll
  for (int g = 0; g < 4; ++g){
    const unsigned short* arow = xtb + (size_t)(b*8192 + q0 + 16*g + nl)*96 + quad*8;
    af[g][0] = *(const s16x8*)(arow);
    af[g][1] = *(const s16x8*)(arow + 32);
    af[g][2] = *(const s16x8*)(arow + 64);
  }
  float x2qA[4][4];
  #pragma unroll
  for (int g = 0; g < 4; ++g)
    #pragma unroll
    for (int r = 0; r < 4; ++r)
      x2qA[g][r] = x2[b*8192 + q0 + 16*g + quad*4 + r];

  // ---- phase 1: wave w thresholds its own group (bisection on mate scores) ----
  {
    const unsigned short* arow = xtb + (size_t)(b*8192 + q0 + 16*w + nl)*96 + quad*8;
    s16x8 aw0 = *(const s16x8*)(arow);
    s16x8 aw1 = *(const s16x8*)(arow + 32);
    s16x8 aw2 = *(const s16x8*)(arow + 64);
    float x2qw[4];
    #pragma unroll
    for (int r = 0; r < 4; ++r) x2qw[r] = x2[b*8192 + q0 + 16*w + quad*4 + r];
    int stroke = q0 >> 8;
    f32x4 us[16];
    #pragma unroll
    for (int ss = 0; ss < 16; ++ss){
      int c0 = stroke*256 + ss*16;
      const unsigned short* brow = cb + (size_t)(c0 + nl)*96 + quad*8;
      s16x8 b0 = *(const s16x8*)(brow);
      s16x8 b1 = *(const s16x8*)(brow + 32);
      s16x8 b2 = *(const s16x8*)(brow + 64);
      us[ss] = score16v(aw0, aw1, aw2, b0, b1, b2, x2b[c0 + nl], x2qw);
    }
    float lo0=-4096.f, lo1=-4096.f, lo2=-4096.f, lo3=-4096.f;
    float hi0=257.f,   hi1=257.f,   hi2=257.f,   hi3=257.f;
    for (int it = 0; it < 13; ++it){
      float t0 = 0.5f*(lo0+hi0), t1 = 0.5f*(lo1+hi1), t2 = 0.5f*(lo2+hi2), t3 = 0.5f*(lo3+hi3);
      int c0=0, c1=0, c2=0, c3=0;
      #pragma unroll
      for (int ss = 0; ss < 16; ++ss){
        c0 += (us[ss][0] >= t0);
        c1 += (us[ss][1] >= t1);
        c2 += (us[ss][2] >= t2);
        c3 += (us[ss][3] >= t3);
      }
      unsigned p01 = (unsigned)c0 | ((unsigned)c1 << 16);
      unsigned p23 = (unsigned)c2 | ((unsigned)c3 << 16);
      #pragma unroll
      for (int off = 1; off <= 8; off <<= 1){
        p01 += (unsigned)__shfl_xor((int)p01, off);
        p23 += (unsigned)__shfl_xor((int)p23, off);
      }
      c0 = (int)(p01 & 0xFFFFu); c1 = (int)(p01 >> 16);
      c2 = (int)(p23 & 0xFFFFu); c3 = (int)(p23 >> 16);
      if (c0 >= 64) lo0 = t0; else hi0 = t0;
      if (c1 >= 64) lo1 = t1; else hi1 = t1;
      if (c2 >= 64) lo2 = t2; else hi2 = t2;
      if (c3 >= 64) lo3 = t3; else hi3 = t3;
    }
    if (nl == 0){
      thrS[16*w + quad*4 + 0] = lo0;
      thrS[16*w + quad*4 + 1] = lo1;
      thrS[16*w + quad*4 + 2] = lo2;
      thrS[16*w + quad*4 + 3] = lo3;
    }
  }
  __syncthreads();
  float thrA[4][4];
  #pragma unroll
  for (int g = 0; g < 4; ++g)
    #pragma unroll
    for (int r = 0; r < 4; ++r)
      thrA[g][r] = thrS[16*g + quad*4 + r];

  // ---- phase 2: wave w scans its 2048-cand range for ALL 64 queries (prefetched) ----
  {
    int s0w = w*128;
    s16x8 nb0, nb1, nb2; float nx2;
    {
      const unsigned short* brow = cb + (size_t)(s0w*16 + nl)*96 + quad*8;
      nb0 = *(const s16x8*)(brow);
      nb1 = *(const s16x8*)(brow + 32);
      nb2 = *(const s16x8*)(brow + 64);
      nx2 = x2b[s0w*16 + nl];
    }
    for (int si = 0; si < 128; ++si){
      s16x8 b0 = nb0, b1 = nb1, b2 = nb2;
      float x2c = nx2;
      int s = s0w + si;
      int sp = (si < 127) ? s + 1 : s;
      {
        const unsigned short* brow = cb + (size_t)(sp*16 + nl)*96 + quad*8;
        nb0 = *(const s16x8*)(brow);
        nb1 = *(const s16x8*)(brow + 32);
        nb2 = *(const s16x8*)(brow + 64);
        nx2 = x2b[sp*16 + nl];
      }
      int cand = s*16 + nl;
      #pragma unroll
      for (int g = 0; g < 4; ++g){
        f32x4 u = score16v(af[g][0], af[g][1], af[g][2], b0, b1, b2, x2c, x2qA[g]);
        #pragma unroll
        for (int r = 0; r < 4; ++r){
          if (u[r] >= thrA[g][r]){
            int ql = 16*g + quad*4 + r;
            unsigned pos = atomicAdd(&cnt[ql], 1u);
            if (pos < 256u) idxL[ql*256 + pos] = (unsigned short)cand;
          }
        }
      }
    }
  }
  __syncthreads();

  // ---- phase 3: exact fp32 rerank (wave-private, chunk-prefetched) ----
  {
    float* rr = (float*)(SM + 33536) + w*776;       // [8 rows][97]
    float* distQ = (float*)(SM + 45952) + w*256;
    int part = lane & 7, candl = lane >> 3;
    for (int rep = 0; rep < 16; ++rep){
      int q = 16*w + rep;
      int gq = b*8192 + q0 + q;
      unsigned craw = cnt[q];
      int cq = (int)(craw < 256u ? craw : 256u);
      float4 xq4[3];
      { const float4* xqp = (const float4*)(xt + (size_t)gq*96 + part*12);
        xq4[0] = xqp[0]; xq4[1] = xqp[1]; xq4[2] = xqp[2]; }
      int nch = (cq + 7) >> 3;
      float4 pv[3];
      auto loadChunk = [&](int ch, float4* dst){
        #pragma unroll
        for (int i = 0; i < 3; ++i){
          int f = i*64 + lane;
          int r_ = f / 24, c4 = f - r_*24;
          int k = ch*8 + r_;
          int kk = k < cq ? k : 0;
          int j = idxL[q*256 + kk];
          dst[i] = *(const float4*)(xt + (size_t)(b*8192 + j)*96 + c4*4);
        }
      };
      if (nch > 0) loadChunk(0, pv);
      for (int ch = 0; ch < nch; ++ch){
        float4 cv0 = pv[0], cv1 = pv[1], cv2 = pv[2];
        if (ch + 1 < nch) loadChunk(ch + 1, pv);
        {
          float4 cvs[3] = {cv0, cv1, cv2};
          #pragma unroll
          for (int i = 0; i < 3; ++i){
            int f = i*64 + lane;
            int r_ = f / 24, c4 = f - r_*24;
            float* dst = rr + r_*97 + c4*4;
            dst[0] = cvs[i].x; dst[1] = cvs[i].y; dst[2] = cvs[i].z; dst[3] = cvs[i].w;
          }
        }
        float acc = 0.f;
        const float* rrr = rr + candl*97 + part*12;
        #pragma unroll
        for (int i = 0; i < 3; ++i){
          float4 xv = xq4[i];
          float d0 = rrr[i*4+0] - xv.x, d1 = rrr[i*4+1] - xv.y;
          float d2 = rrr[i*4+2] - xv.z, d3 = rrr[i*4+3] - xv.w;
          acc += d0*d0 + d1*d1 + d2*d2 + d3*d3;
        }
        acc += __shfl_xor(acc, 1);
        acc += __shfl_xor(acc, 2);
        acc += __shfl_xor(acc, 4);
        if (part == 0) distQ[ch*8 + candl] = acc;
      }
      float dsl[4]; int ils[4]; bool alive[4];
      #pragma unroll
      for (int s2 = 0; s2 < 4; ++s2){
        int k = (s2 << 6) + lane;
        bool a = k < cq;
        alive[s2] = a;
        ils[s2] = a ? (int)idxL[q*256 + k] : -1;
        dsl[s2] = a ? distQ[k] : -1.f;
      }
      int A = cq;
      while (A > 50){
        float wd = -1.f; int wi = -1; int wsl = -1;
        #pragma unroll
        for (int s2 = 0; s2 < 4; ++s2)
          if (alive[s2] && (dsl[s2] > wd || (dsl[s2] == wd && ils[s2] > wi))){
            wd = dsl[s2]; wi = ils[s2]; wsl = s2;
          }
        float gd = wd; int gi = wi;
        #pragma unroll
        for (int off = 32; off > 0; off >>= 1){
          float od = __shfl_xor(gd, off); int oi = __shfl_xor(gi, off);
          if (od > gd || (od == gd && oi > gi)){ gd = od; gi = oi; }
        }
        if (wsl >= 0 && wi == gi && wd == gd) alive[wsl] = false;
        --A;
      }
      #pragma unroll
      for (int s2 = 0; s2 < 4; ++s2){
        if (alive[s2]){
          unsigned pos = atomicAdd(&ocnt[q], 1u);
          if (pos < 50u) i50[(size_t)gq*50 + pos] = ils[s2];
        }
      }
    }
  }
}

// ---------------- EdgeConv factorization via MFMA (hi/lo split) ----------------
__global__ __launch_bounds__(256) void k_g1p1(const float* __restrict__ xt,
                                              const unsigned short* __restrict__ w1h,
                                              const unsigned short* __restrict__ w1l,
                                              const float* __restrict__ bb1,
                                              float* __restrict__ g1,
                                              float* __restrict__ p1){
  int tid = threadIdx.x, w = tid >> 6, lane = tid & 63;
  int nl = lane & 15, quad = lane >> 4;
  int p0 = blockIdx.x*64;
  // A-frags: 16 points per wave, hi/lo split of xt rows
  s16x8 ah[3], al[3];
  {
    const float* arow = xt + (size_t)(p0 + 16*w + nl)*96;
    #pragma unroll
    for (int kc = 0; kc < 3; ++kc){
      float4 v0 = *(const float4*)(arow + kc*32 + quad*8);
      float4 v1 = *(const float4*)(arow + kc*32 + quad*8 + 4);
      float tv[8] = {v0.x, v0.y, v0.z, v0.w, v1.x, v1.y, v1.z, v1.w};
      #pragma unroll
      for (int i = 0; i < 8; ++i){
        unsigned bits = __float_as_uint(tv[i]);
        ah[kc][i] = (short)(bits >> 16);
        float hv = __uint_as_float(bits & 0xFFFF0000u);
        al[kc][i] = (short)rne_bf16(tv[i] - hv);
      }
    }
  }
  #pragma unroll
  for (int nt = 0; nt < 7; ++nt){
    f32x4 Ca = {0.f,0.f,0.f,0.f}, Cc = {0.f,0.f,0.f,0.f};
    #pragma unroll
    for (int kc = 0; kc < 3; ++kc){
      size_t oa = (size_t)(nt*16 + nl)*96 + kc*32 + quad*8;
      size_t oc = (size_t)(nt*16 + 112 + nl)*96 + kc*32 + quad*8;
      s16x8 bha = *(const s16x8*)(w1h + oa);
      s16x8 bla = *(const s16x8*)(w1l + oa);
      s16x8 bhc = *(const s16x8*)(w1h + oc);
      s16x8 blc = *(const s16x8*)(w1l + oc);
      Ca = __builtin_amdgcn_mfma_f32_16x16x32_bf16(ah[kc], bha, Ca, 0, 0, 0);
      Ca = __builtin_amdgcn_mfma_f32_16x16x32_bf16(al[kc], bha, Ca, 0, 0, 0);
      Ca = __builtin_amdgcn_mfma_f32_16x16x32_bf16(ah[kc], bla, Ca, 0, 0, 0);
      Cc = __builtin_amdgcn_mfma_f32_16x16x32_bf16(ah[kc], bhc, Cc, 0, 0, 0);
      Cc = __builtin_amdgcn_mfma_f32_16x16x32_bf16(al[kc], bhc, Cc, 0, 0, 0);
      Cc = __builtin_amdgcn_mfma_f32_16x16x32_bf16(ah[kc], blc, Cc, 0, 0, 0);
    }
    int n = nt*16 + nl;
    float bias = (n < 110) ? bb1[n] : 0.f;
    #pragma unroll
    for (int r = 0; r < 4; ++r){
      int pt = p0 + 16*w + quad*4 + r;
      g1[(size_t)pt*112 + n] = Ca[r];
      p1[(size_t)pt*112 + n] = Cc[r] - Ca[r] + bias;
    }
  }
}

// ---------------- dense EdgeConv: MFMA (hi/lo split) + max over 50 ----------------
__global__ __launch_bounds__(256) void k_econv(const float* __restrict__ g1,
                                               const float* __restrict__ p1,
                                               const int* __restrict__ i50,
                                               const unsigned short* __restrict__ w2h,
                                               const unsigned short* __restrict__ w2l,
                                               const float* __restrict__ bb2,
                                               float* __restrict__ cin){
  __shared__ __align__(16) unsigned short BH[2*64*136];   // W2 hi | lo, row stride 136
  unsigned short* bhi = BH;
  unsigned short* blo = BH + 64*136;
  int tid = threadIdx.x, w = tid >> 6, lane = tid & 63;
  int nl = lane & 15, quad = lane >> 4;
  for (int idx = tid; idx < 8192; idx += 256){
    int row = idx >> 7, k = idx & 127;
    bhi[row*136 + k] = w2h[idx];
    blo[row*136 + k] = w2l[idx];
  }
  __syncthreads();

  int gq = blockIdx.x*4 + w;
  int b = gq >> 13;
  const int* jrow = i50 + (size_t)gq*50;
  const float* pr = p1 + (size_t)gq*112;
  float4 pf[8];
  #pragma unroll
  for (int ks = 0; ks < 4; ++ks){
    if (ks < 3 || quad < 2){
      pf[2*ks]   = *(const float4*)(pr + ks*32 + quad*8);
      pf[2*ks+1] = *(const float4*)(pr + ks*32 + quad*8 + 4);
    } else {
      pf[2*ks] = make_float4(0.f,0.f,0.f,0.f); pf[2*ks+1] = make_float4(0.f,0.f,0.f,0.f);
    }
  }
  float m4[4] = {-3.4e38f, -3.4e38f, -3.4e38f, -3.4e38f};

  for (int rt = 0; rt < 4; ++rt){
    int e = rt*16 + nl;
    int j = jrow[e < 50 ? e : 49];
    const float* gr = g1 + (size_t)(b*8192 + j)*112;
    s16x8 ah[4], al[4];
    #pragma unroll
    for (int ks = 0; ks < 4; ++ks){
      if (ks == 3 && quad >= 2){
        #pragma unroll
        for (int i = 0; i < 8; ++i){ ah[3][i] = 0; al[3][i] = 0; }
      } else {
        int off = ks*32 + quad*8;
        float4 g0  = *(const float4*)(gr + off);
        float4 g1v = *(const float4*)(gr + off + 4);
        float4 p0v = pf[2*ks], p1v = pf[2*ks+1];
        float tv[8] = { leaky(g0.x+p0v.x),  leaky(g0.y+p0v.y),  leaky(g0.z+p0v.z),  leaky(g0.w+p0v.w),
                        leaky(g1v.x+p1v.x), leaky(g1v.y+p1v.y), leaky(g1v.z+p1v.z), leaky(g1v.w+p1v.w) };
        #pragma unroll
        for (int i = 0; i < 8; ++i){
          unsigned bits = __float_as_uint(tv[i]);
          ah[ks][i] = (short)(bits >> 16);
          float hv = __uint_as_float(bits & 0xFFFF0000u);
          al[ks][i] = (short)rne_bf16(tv[i] - hv);
        }
      }
    }
    f32x4 C[4] = {{0.f,0.f,0.f,0.f},{0.f,0.f,0.f,0.f},{0.f,0.f,0.f,0.f},{0.f,0.f,0.f,0.f}};
    #pragma unroll
    for (int ks = 0; ks < 4; ++ks){
      int ko = ks*64 + quad*16;
      #pragma unroll
      for (int ct = 0; ct < 4; ++ct){
        const char* rp = (const char*)bhi + (ct*16 + nl)*272 + ko;
        s16x8 bh  = *(const s16x8*)(rp);
        s16x8 blv = *(const s16x8*)(rp + 64*136*2);
        C[ct] = __builtin_amdgcn_mfma_f32_16x16x32_bf16(ah[ks], bh,  C[ct], 0, 0, 0);
        C[ct] = __builtin_amdgcn_mfma_f32_16x16x32_bf16(al[ks], bh,  C[ct], 0, 0, 0);
        C[ct] = __builtin_amdgcn_mfma_f32_16x16x32_bf16(ah[ks], blv, C[ct], 0, 0, 0);
      }
    }
    if (rt < 3){
      #pragma unroll
      for (int ct = 0; ct < 4; ++ct)
        #pragma unroll
        for (int r = 0; r < 4; ++r) m4[ct] = fmaxf(m4[ct], C[ct][r]);
    } else {
      if (quad == 0){
        #pragma unroll
        for (int ct = 0; ct < 4; ++ct){
          m4[ct] = fmaxf(m4[ct], C[ct][0]);
          m4[ct] = fmaxf(m4[ct], C[ct][1]);
        }
      }
    }
  }
  #pragma unroll
  for (int ct = 0; ct < 4; ++ct){
    m4[ct] = fmaxf(m4[ct], __shfl_xor(m4[ct], 16));
    m4[ct] = fmaxf(m4[ct], __shfl_xor(m4[ct], 32));
  }
  if (quad == 0){
    #pragma unroll
    for (int ct = 0; ct < 4; ++ct){
      int o = ct*16 + nl;
      cin[(size_t)gq*64 + o] = leaky(m4[ct] + bb2[o]);
    }
  }
}

// ---------------- downsample conv (1,3) stride (1,2) pad (0,1) ----------------
__global__ __launch_bounds__(256) void k_down(const float* __restrict__ cin,
                                              const float* __restrict__ wdt,
                                              const float* __restrict__ bias,
                                              float* __restrict__ outp){
  int blk = blockIdx.x;
  int b = blk >> 8, r = blk & 255, s = r >> 3, oq = r & 7;
  int t = threadIdx.x;
  __shared__ __align__(16) float L[34*68];
  for (int k = t; k < 34*64; k += 256){
    int rr = k >> 6, i = k & 63;
    int pp = oq*32 - 1 + rr;
    float v = 0.f;
    if (pp >= 0 && pp < 256) v = cin[(size_t)(b*8192 + s*256 + pp)*64 + i];
    L[rr*68 + i] = v;
  }
  __syncthreads();
  #pragma unroll
  for (int kk = 0; kk < 4; ++kk){
    int ow = kk*256 + t;
    int o = ow >> 4, wl = ow & 15;
    float acc = bias[o];
    #pragma unroll
    for (int tt = 0; tt < 3; ++tt){
      int rr = 2*wl + tt;
      const float4* lv4 = (const float4*)(L + rr*68);
      const float4* wv4 = (const float4*)(wdt + tt*4096 + o*64);
      #pragma unroll
      for (int i4 = 0; i4 < 16; ++i4){
        float4 lv = lv4[i4], wv = wv4[i4];
        acc += wv.x*lv.x + wv.y*lv.y + wv.z*lv.z + wv.w*lv.w;
      }
    }
    int w_ = oq*16 + wl;
    outp[16384 + (size_t)((b*64 + o)*32 + s)*128 + w_] = leaky(acc);
  }
}

extern "C" void kernel_launch(void* const* d_in, const int* in_sizes, int n_in,
                              void* d_out, int out_size, void* d_ws, size_t ws_size,
                              hipStream_t stream){
  (void)in_sizes; (void)n_in; (void)out_size; (void)ws_size;
  const float* sparse = (const float*)d_in[0];
  const float* dense  = (const float*)d_in[1];
  const float* spW1   = (const float*)d_in[2];
  const float* spb1   = (const float*)d_in[3];
  const float* spW2   = (const float*)d_in[4];
  const float* spb2   = (const float*)d_in[5];
  const float* dnW1   = (const float*)d_in[6];
  const float* dnb1   = (const float*)d_in[7];
  const float* dnW2   = (const float*)d_in[8];
  const float* dnb2   = (const float*)d_in[9];
  const float* dsW    = (const float*)d_in[10];
  const float* dsb    = (const float*)d_in[11];
  float* out = (float*)d_out;

  float* w    = (float*)d_ws;                  // 63.5 MB
  float* xt   = w;                             // 3,145,728
  float* x2   = w + 3145728;                   //    32,768
  float* g1   = w + 3178496;                   // 3,670,016 (stride 112)
  float* p1   = w + 6848512;                   // 3,670,016
  int*   i50  = (int*)(w + 10518528);          // 1,638,400
  float* cin  = w + 12156928;                  // 2,097,152
  float* xtsp = w + 14254080;                  //    12,288
  unsigned short* xtb = (unsigned short*)(w + 14266368);  // 3,145,728 u16
  unsigned short* w1h = (unsigned short*)(w + 15839232);  // 21504 u16
  unsigned short* w1l = (unsigned short*)(w + 15849984);
  unsigned short* w2h = (unsigned short*)(w + 15860736);  // 8192 u16
  unsigned short* w2l = (unsigned short*)(w + 15864832);
  float* wdt  = w + 15868928;                  // 12,288

  k_prep        <<<164,  256, 0, stream>>>(dnW1, dnW2, dsW, w1h, w1l, w2h, w2l, wdt);
  k_build_xt    <<<512,  256, 0, stream>>>(dense, sparse, xt, xtb, x2);
  k_sparse_union<<<128,  256, 0, stream>>>(sparse, dense, xtsp);
  k_sparse_gcn  <<<128,  192, 0, stream>>>(xtsp, spW1, spb1, spW2, spb2, out);
  k_knn         <<<512,  256, 0, stream>>>(xtb, x2, xt, i50);
  k_g1p1        <<<512,  256, 0, stream>>>(xt, w1h, w1l, dnb1, g1, p1);
  k_econv       <<<8192, 256, 0, stream>>>(g1, p1, i50, w2h, w2l, dnb2, cin);
  k_down        <<<1024, 256, 0, stream>>>(cin, wdt, dsb, out);
}

// Round 7
// 628.729 us; speedup vs baseline: 9.3406x; 1.4039x over previous
//
#include <hip/hip_runtime.h>

// SDGraphUNet on MI355X — round 6.
//  k_knn: phase-3 selection rewritten as rank-based (packed u64 keys in LDS,
//  broadcast reads, no shfl-butterfly elimination, no output atomics).
//  Selection order identical to R5 -> bit-identical i50 set.
//  k_econv: 512-thread blocks (8 waves share one W2 staging), grid 4096.
//
// ws (floats): xt 3145728 | x2 32768 | g1 3670016 | p1 3670016 | i50 1638400(int)
//  | cin 2097152 | xtsp 12288 | xtb(u16) 1572864 | w1h/w1l/w2h/w2l | wdt
//  total = 63.5 MB

#define LEAKK 0.2f

typedef short s16x8 __attribute__((ext_vector_type(8)));
typedef float f32x4 __attribute__((ext_vector_type(4)));

__device__ __forceinline__ float leaky(float x){ return x > 0.f ? x : LEAKK*x; }
__device__ __forceinline__ unsigned rne_bf16(float v){
  unsigned bits = __float_as_uint(v);
  return (bits + 0x7FFFu + ((bits >> 16) & 1u)) >> 16;
}

// ---------------- prep: hi/lo splits + Wd transpose ----------------
__global__ __launch_bounds__(256) void k_prep(const float* __restrict__ W1,
                                              const float* __restrict__ W2,
                                              const float* __restrict__ Wd,
                                              unsigned short* __restrict__ w1h,
                                              unsigned short* __restrict__ w1l,
                                              unsigned short* __restrict__ w2h,
                                              unsigned short* __restrict__ w2l,
                                              float* __restrict__ wdt){
  int idx = blockIdx.x*256 + threadIdx.x;       // < 41984
  if (idx < 21504){
    int row = idx / 96, k = idx - row*96;
    float v = 0.f;
    if (row < 110) v = W1[row*192 + k];
    else if (row >= 112 && row < 222) v = W1[(row - 112)*192 + 96 + k];
    unsigned bits = __float_as_uint(v);
    w1h[idx] = (unsigned short)(bits >> 16);
    float hv = __uint_as_float(bits & 0xFFFF0000u);
    w1l[idx] = (unsigned short)rne_bf16(v - hv);
  } else if (idx < 29696){
    int j = idx - 21504;
    int row = j >> 7, k = j & 127;
    float v = (k < 110) ? W2[row*110 + k] : 0.f;
    unsigned bits = __float_as_uint(v);
    w2h[j] = (unsigned short)(bits >> 16);
    float hv = __uint_as_float(bits & 0xFFFF0000u);
    w2l[j] = (unsigned short)rne_bf16(v - hv);
  } else if (idx < 41984){
    int j = idx - 29696;                        // tt*4096 + o*64 + i
    int tt = j >> 12, rest = j & 4095, o = rest >> 6, i = rest & 63;
    wdt[j] = Wd[(o*64 + i)*3 + tt];
  }
}

// ---------------- build dense union features (fp32 + bf16) + x2 ----------------
__global__ __launch_bounds__(256) void k_build_xt(const float* __restrict__ dense,
                                                  const float* __restrict__ sparse,
                                                  float* __restrict__ xt,
                                                  unsigned short* __restrict__ xtb,
                                                  float* __restrict__ x2){
  __shared__ float D[32*65];
  __shared__ float sArr[64];
  int blk = blockIdx.x;               // ((b*32+s)*4 + q4)
  int q4 = blk & 3, bs = blk >> 2, b = bs >> 5, s = bs & 31;
  int tid = threadIdx.x;
  if (tid < 64) sArr[tid] = sparse[(b*64 + tid)*32 + s];
  for (int i = tid; i < 2048; i += 256){
    int c = i >> 6, pp = i & 63;
    D[c*65 + pp] = dense[(((b*32 + c)*32 + s) << 8) + q4*64 + pp];
  }
  __syncthreads();
  float ss = 0.f;
  #pragma unroll
  for (int ch = 0; ch < 64; ++ch){ float v = sArr[ch]; ss = __builtin_fmaf(v, v, ss); }
  size_t base = ((size_t)b*8192 + s*256 + q4*64)*96;
  for (int i = tid; i < 6144; i += 256){
    int pp = i / 96, c = i - pp*96;
    float v = (c < 32) ? D[c*65 + pp] : sArr[c - 32];
    xt[base + i] = v;
    xtb[base + i] = (unsigned short)rne_bf16(v);
  }
  if (tid < 64){
    float a = ss;
    #pragma unroll
    for (int c = 0; c < 32; ++c){ float v = D[c*65 + tid]; a = __builtin_fmaf(v, v, a); }
    x2[b*8192 + s*256 + q4*64 + tid] = a;
  }
}

// ---------------- sparse union (max over points + concat) ----------------
__global__ void k_sparse_union(const float* __restrict__ sp, const float* __restrict__ dn,
                               float* __restrict__ xtsp){
  int b = blockIdx.x >> 5, i = blockIdx.x & 31;
  int w = threadIdx.x >> 6, l = threadIdx.x & 63;
  if (w == 0) xtsp[(b*32 + i)*96 + l] = sp[(b*64 + l)*32 + i];
  for (int c = w; c < 32; c += 4){
    const float* row = dn + (((size_t)(b*32 + c)*32 + i) << 8);
    float v = fmaxf(fmaxf(row[l], row[l+64]), fmaxf(row[l+128], row[l+192]));
    for (int off = 32; off > 0; off >>= 1) v = fmaxf(v, __shfl_down(v, off));
    if (l == 0) xtsp[(b*32 + i)*96 + 64 + c] = v;
  }
}

// ---------------- sparse GCN (k=2 over 32 strokes) ----------------
__global__ void k_sparse_gcn(const float* __restrict__ xtsp,
                             const float* __restrict__ W1, const float* __restrict__ bb1,
                             const float* __restrict__ W2, const float* __restrict__ bb2,
                             float* __restrict__ outp){
  int b = blockIdx.x >> 5, i = blockIdx.x & 31, t = threadIdx.x;
  __shared__ float X[32*96];
  __shared__ float x2l[32], dd[32];
  __shared__ int nb[2];
  for (int k = t; k < 3072; k += 192) X[k] = xtsp[b*3072 + k];
  __syncthreads();
  if (t < 32){
    float s = 0.f;
    for (int c = 0; c < 96; ++c){ float v = X[t*96+c]; s += v*v; }
    x2l[t] = s;
  }
  __syncthreads();
  if (t < 32){
    float dot = 0.f;
    for (int c = 0; c < 96; ++c) dot += X[i*96+c]*X[t*96+c];
    dd[t] = x2l[i] - 2.f*dot + x2l[t];
  }
  __syncthreads();
  if (t == 0){
    int s0 = -1, s1 = -1;
    for (int j = 0; j < 32; ++j){
      float dj = dd[j];
      if (s0 < 0 || dj < dd[s0]){ s1 = s0; s0 = j; }
      else if (s1 < 0 || dj < dd[s1]){ s1 = j; }
    }
    nb[0] = s0; nb[1] = s1;
  }
  __syncthreads();
  __shared__ __align__(16) float E[192];
  __shared__ __align__(16) float H1[156];
  float acc = -3.4e38f;
  for (int n = 0; n < 2; ++n){
    int j = nb[n];
    if (t < 96){ E[t] = X[j*96+t] - X[i*96+t]; E[96+t] = X[i*96+t]; }
    __syncthreads();
    if (t < 156){
      float h = bb1[t];
      const float* wr = W1 + t*192;
      for (int k = 0; k < 192; ++k) h += E[k]*wr[k];
      H1[t] = leaky(h);
    }
    __syncthreads();
    if (t < 128){
      float h = bb2[t];
      const float* wr = W2 + t*156;
      for (int m = 0; m < 156; ++m) h += H1[m]*wr[m];
      acc = fmaxf(acc, leaky(h));
    }
    __syncthreads();
  }
  if (t < 128) outp[(b*128 + t)*32 + i] = acc;
}

// ---- 16 queries x 16 cands -> u = 256 - d_approx; shared by both kNN phases ----
__device__ __forceinline__ f32x4 score16v(s16x8 a0, s16x8 a1, s16x8 a2,
                                          s16x8 b0, s16x8 b1, s16x8 b2,
                                          float x2c, const float* x2q){
  f32x4 acc = {0.f,0.f,0.f,0.f};
  acc = __builtin_amdgcn_mfma_f32_16x16x32_bf16(a0, b0, acc, 0, 0, 0);
  acc = __builtin_amdgcn_mfma_f32_16x16x32_bf16(a1, b1, acc, 0, 0, 0);
  acc = __builtin_amdgcn_mfma_f32_16x16x32_bf16(a2, b2, acc, 0, 0, 0);
  f32x4 u;
  #pragma unroll
  for (int r = 0; r < 4; ++r)
    u[r] = (__builtin_fmaf(2.f, acc[r], -x2c) - x2q[r]) + 256.f;
  return u;
}

// ---------------- fused kNN v4 (rank-based exact selection) ----------------
__global__ __launch_bounds__(256) void k_knn(const unsigned short* __restrict__ xtb,
                                             const float* __restrict__ x2,
                                             const float* __restrict__ xt,
                                             int* __restrict__ i50){
  // idxL u16[64][256]:0..32768 | cnt@32768 | thrS@33280
  // rr 4x776f @33536..45952 | distK 4x256 u64 @45952..54144
  __shared__ __align__(16) char SM[54144];
  unsigned short* idxL = (unsigned short*)SM;
  unsigned* cnt  = (unsigned*)(SM + 32768);
  float*    thrS = (float*)(SM + 33280);

  // XCD-aware swizzle: batch pinned to an XCD pair
  int b = (blockIdx.x & 7) >> 1;
  int chunkI = ((blockIdx.x >> 3) << 1) | (blockIdx.x & 1);
  int q0 = chunkI << 6;
  int tid = threadIdx.x, w = tid >> 6, lane = tid & 63;
  int nl = lane & 15, quad = lane >> 4;

  if (tid < 64) cnt[tid] = 0u;

  const unsigned short* cb = xtb + (size_t)b*8192*96;
  const float* x2b = x2 + b*8192;

  // A-frags for ALL 4 query groups (phase 2)
  s16x8 af[4][3];
  #pragma unroll
  for (int g = 0; g < 4; ++g){
    const unsigned short* arow = xtb + (size_t)(b*8192 + q0 + 16*g + nl)*96 + quad*8;
    af[g][0] = *(const s16x8*)(arow);
    af[g][1] = *(const s16x8*)(arow + 32);
    af[g][2] = *(const s16x8*)(arow + 64);
  }
  float x2qA[4][4];
  #pragma unroll
  for (int g = 0; g < 4; ++g)
    #pragma unroll
    for (int r = 0; r < 4; ++r)
      x2qA[g][r] = x2[b*8192 + q0 + 16*g + quad*4 + r];

  // ---- phase 1: wave w thresholds its own group (bisection on mate scores) ----
  {
    const unsigned short* arow = xtb + (size_t)(b*8192 + q0 + 16*w + nl)*96 + quad*8;
    s16x8 aw0 = *(const s16x8*)(arow);
    s16x8 aw1 = *(const s16x8*)(arow + 32);
    s16x8 aw2 = *(const s16x8*)(arow + 64);
    float x2qw[4];
    #pragma unroll
    for (int r = 0; r < 4; ++r) x2qw[r] = x2[b*8192 + q0 + 16*w + quad*4 + r];
    int stroke = q0 >> 8;
    f32x4 us[16];
    #pragma unroll
    for (int ss = 0; ss < 16; ++ss){
      int c0 = stroke*256 + ss*16;
      const unsigned short* brow = cb + (size_t)(c0 + nl)*96 + quad*8;
      s16x8 b0 = *(const s16x8*)(brow);
      s16x8 b1 = *(const s16x8*)(brow + 32);
      s16x8 b2 = *(const s16x8*)(brow + 64);
      us[ss] = score16v(aw0, aw1, aw2, b0, b1, b2, x2b[c0 + nl], x2qw);
    }
    float lo0=-4096.f, lo1=-4096.f, lo2=-4096.f, lo3=-4096.f;
    float hi0=257.f,   hi1=257.f,   hi2=257.f,   hi3=257.f;
    for (int it = 0; it < 13; ++it){
      float t0 = 0.5f*(lo0+hi0), t1 = 0.5f*(lo1+hi1), t2 = 0.5f*(lo2+hi2), t3 = 0.5f*(lo3+hi3);
      int c0=0, c1=0, c2=0, c3=0;
      #pragma unroll
      for (int ss = 0; ss < 16; ++ss){
        c0 += (us[ss][0] >= t0);
        c1 += (us[ss][1] >= t1);
        c2 += (us[ss][2] >= t2);
        c3 += (us[ss][3] >= t3);
      }
      unsigned p01 = (unsigned)c0 | ((unsigned)c1 << 16);
      unsigned p23 = (unsigned)c2 | ((unsigned)c3 << 16);
      #pragma unroll
      for (int off = 1; off <= 8; off <<= 1){
        p01 += (unsigned)__shfl_xor((int)p01, off);
        p23 += (unsigned)__shfl_xor((int)p23, off);
      }
      c0 = (int)(p01 & 0xFFFFu); c1 = (int)(p01 >> 16);
      c2 = (int)(p23 & 0xFFFFu); c3 = (int)(p23 >> 16);
      if (c0 >= 64) lo0 = t0; else hi0 = t0;
      if (c1 >= 64) lo1 = t1; else hi1 = t1;
      if (c2 >= 64) lo2 = t2; else hi2 = t2;
      if (c3 >= 64) lo3 = t3; else hi3 = t3;
    }
    if (nl == 0){
      thrS[16*w + quad*4 + 0] = lo0;
      thrS[16*w + quad*4 + 1] = lo1;
      thrS[16*w + quad*4 + 2] = lo2;
      thrS[16*w + quad*4 + 3] = lo3;
    }
  }
  __syncthreads();
  float thrA[4][4];
  #pragma unroll
  for (int g = 0; g < 4; ++g)
    #pragma unroll
    for (int r = 0; r < 4; ++r)
      thrA[g][r] = thrS[16*g + quad*4 + r];

  // ---- phase 2: wave w scans its 2048-cand range for ALL 64 queries (prefetched) ----
  {
    int s0w = w*128;
    s16x8 nb0, nb1, nb2; float nx2;
    {
      const unsigned short* brow = cb + (size_t)(s0w*16 + nl)*96 + quad*8;
      nb0 = *(const s16x8*)(brow);
      nb1 = *(const s16x8*)(brow + 32);
      nb2 = *(const s16x8*)(brow + 64);
      nx2 = x2b[s0w*16 + nl];
    }
    for (int si = 0; si < 128; ++si){
      s16x8 b0 = nb0, b1 = nb1, b2 = nb2;
      float x2c = nx2;
      int s = s0w + si;
      int sp = (si < 127) ? s + 1 : s;
      {
        const unsigned short* brow = cb + (size_t)(sp*16 + nl)*96 + quad*8;
        nb0 = *(const s16x8*)(brow);
        nb1 = *(const s16x8*)(brow + 32);
        nb2 = *(const s16x8*)(brow + 64);
        nx2 = x2b[sp*16 + nl];
      }
      int cand = s*16 + nl;
      #pragma unroll
      for (int g = 0; g < 4; ++g){
        f32x4 u = score16v(af[g][0], af[g][1], af[g][2], b0, b1, b2, x2c, x2qA[g]);
        #pragma unroll
        for (int r = 0; r < 4; ++r){
          if (u[r] >= thrA[g][r]){
            int ql = 16*g + quad*4 + r;
            unsigned pos = atomicAdd(&cnt[ql], 1u);
            if (pos < 256u) idxL[ql*256 + pos] = (unsigned short)cand;
          }
        }
      }
    }
  }
  __syncthreads();

  // ---- phase 3: exact fp32 distances + rank-based top-50 (wave-private) ----
  {
    float* rr = (float*)(SM + 33536) + w*776;       // [8 rows][97]
    unsigned long long* distK = (unsigned long long*)(SM + 45952) + w*256;
    int part = lane & 7, candl = lane >> 3;
    for (int rep = 0; rep < 16; ++rep){
      int q = 16*w + rep;
      int gq = b*8192 + q0 + q;
      unsigned craw = cnt[q];
      int cq = (int)(craw < 256u ? craw : 256u);
      float4 xq4[3];
      { const float4* xqp = (const float4*)(xt + (size_t)gq*96 + part*12);
        xq4[0] = xqp[0]; xq4[1] = xqp[1]; xq4[2] = xqp[2]; }
      int nch = (cq + 7) >> 3;
      float4 pv[3];
      auto loadChunk = [&](int ch, float4* dst){
        #pragma unroll
        for (int i = 0; i < 3; ++i){
          int f = i*64 + lane;
          int r_ = f / 24, c4 = f - r_*24;
          int k = ch*8 + r_;
          int kk = k < cq ? k : 0;
          int j = idxL[q*256 + kk];
          dst[i] = *(const float4*)(xt + (size_t)(b*8192 + j)*96 + c4*4);
        }
      };
      if (nch > 0) loadChunk(0, pv);
      for (int ch = 0; ch < nch; ++ch){
        float4 cv0 = pv[0], cv1 = pv[1], cv2 = pv[2];
        if (ch + 1 < nch) loadChunk(ch + 1, pv);
        {
          float4 cvs[3] = {cv0, cv1, cv2};
          #pragma unroll
          for (int i = 0; i < 3; ++i){
            int f = i*64 + lane;
            int r_ = f / 24, c4 = f - r_*24;
            float* dst = rr + r_*97 + c4*4;
            dst[0] = cvs[i].x; dst[1] = cvs[i].y; dst[2] = cvs[i].z; dst[3] = cvs[i].w;
          }
        }
        float acc = 0.f;
        const float* rrr = rr + candl*97 + part*12;
        #pragma unroll
        for (int i = 0; i < 3; ++i){
          float4 xv = xq4[i];
          float d0 = rrr[i*4+0] - xv.x, d1 = rrr[i*4+1] - xv.y;
          float d2 = rrr[i*4+2] - xv.z, d3 = rrr[i*4+3] - xv.w;
          acc += d0*d0 + d1*d1 + d2*d2 + d3*d3;
        }
        acc += __shfl_xor(acc, 1);
        acc += __shfl_xor(acc, 2);
        acc += __shfl_xor(acc, 4);
        if (part == 0){
          int kk = ch*8 + candl;
          unsigned cidx = (unsigned)idxL[q*256 + kk];   // may be stale for kk>=cq (unused)
          distK[kk] = (((unsigned long long)__float_as_uint(acc)) << 13) | cidx;
        }
      }
      // rank-based selection: key order == (d, idx) lexicographic order
      unsigned long long k0 = 0ull, k1 = 0ull, k2 = 0ull, k3 = 0ull;
      bool h0 = lane < cq, h1 = 64 + lane < cq, h2 = 128 + lane < cq, h3 = 192 + lane < cq;
      if (h0) k0 = distK[lane];
      if (h1) k1 = distK[64 + lane];
      if (h2) k2 = distK[128 + lane];
      if (h3) k3 = distK[192 + lane];
      unsigned r0 = 0, r1 = 0, r2 = 0, r3 = 0;
      if (cq <= 128){
        #pragma unroll 4
        for (int j = 0; j < cq; ++j){
          unsigned long long kj = distK[j];
          r0 += (kj < k0);
          r1 += (kj < k1);
        }
      } else {
        #pragma unroll 4
        for (int j = 0; j < cq; ++j){
          unsigned long long kj = distK[j];
          r0 += (kj < k0); r1 += (kj < k1);
          r2 += (kj < k2); r3 += (kj < k3);
        }
      }
      int* orow = i50 + (size_t)gq*50;
      if (h0 && r0 < 50u) orow[r0] = (int)(k0 & 8191ull);
      if (h1 && r1 < 50u) orow[r1] = (int)(k1 & 8191ull);
      if (h2 && r2 < 50u) orow[r2] = (int)(k2 & 8191ull);
      if (h3 && r3 < 50u) orow[r3] = (int)(k3 & 8191ull);
    }
  }
}

// ---------------- EdgeConv factorization via MFMA (hi/lo split) ----------------
__global__ __launch_bounds__(256) void k_g1p1(const float* __restrict__ xt,
                                              const unsigned short* __restrict__ w1h,
                                              const unsigned short* __restrict__ w1l,
                                              const float* __restrict__ bb1,
                                              float* __restrict__ g1,
                                              float* __restrict__ p1){
  int tid = threadIdx.x, w = tid >> 6, lane = tid & 63;
  int nl = lane & 15, quad = lane >> 4;
  int p0 = blockIdx.x*64;
  s16x8 ah[3], al[3];
  {
    const float* arow = xt + (size_t)(p0 + 16*w + nl)*96;
    #pragma unroll
    for (int kc = 0; kc < 3; ++kc){
      float4 v0 = *(const float4*)(arow + kc*32 + quad*8);
      float4 v1 = *(const float4*)(arow + kc*32 + quad*8 + 4);
      float tv[8] = {v0.x, v0.y, v0.z, v0.w, v1.x, v1.y, v1.z, v1.w};
      #pragma unroll
      for (int i = 0; i < 8; ++i){
        unsigned bits = __float_as_uint(tv[i]);
        ah[kc][i] = (short)(bits >> 16);
        float hv = __uint_as_float(bits & 0xFFFF0000u);
        al[kc][i] = (short)rne_bf16(tv[i] - hv);
      }
    }
  }
  #pragma unroll
  for (int nt = 0; nt < 7; ++nt){
    f32x4 Ca = {0.f,0.f,0.f,0.f}, Cc = {0.f,0.f,0.f,0.f};
    #pragma unroll
    for (int kc = 0; kc < 3; ++kc){
      size_t oa = (size_t)(nt*16 + nl)*96 + kc*32 + quad*8;
      size_t oc = (size_t)(nt*16 + 112 + nl)*96 + kc*32 + quad*8;
      s16x8 bha = *(const s16x8*)(w1h + oa);
      s16x8 bla = *(const s16x8*)(w1l + oa);
      s16x8 bhc = *(const s16x8*)(w1h + oc);
      s16x8 blc = *(const s16x8*)(w1l + oc);
      Ca = __builtin_amdgcn_mfma_f32_16x16x32_bf16(ah[kc], bha, Ca, 0, 0, 0);
      Ca = __builtin_amdgcn_mfma_f32_16x16x32_bf16(al[kc], bha, Ca, 0, 0, 0);
      Ca = __builtin_amdgcn_mfma_f32_16x16x32_bf16(ah[kc], bla, Ca, 0, 0, 0);
      Cc = __builtin_amdgcn_mfma_f32_16x16x32_bf16(ah[kc], bhc, Cc, 0, 0, 0);
      Cc = __builtin_amdgcn_mfma_f32_16x16x32_bf16(al[kc], bhc, Cc, 0, 0, 0);
      Cc = __builtin_amdgcn_mfma_f32_16x16x32_bf16(ah[kc], blc, Cc, 0, 0, 0);
    }
    int n = nt*16 + nl;
    float bias = (n < 110) ? bb1[n] : 0.f;
    #pragma unroll
    for (int r = 0; r < 4; ++r){
      int pt = p0 + 16*w + quad*4 + r;
      g1[(size_t)pt*112 + n] = Ca[r];
      p1[(size_t)pt*112 + n] = Cc[r] - Ca[r] + bias;
    }
  }
}

// ---------------- dense EdgeConv: MFMA (hi/lo split) + max over 50 ----------------
__global__ __launch_bounds__(512) void k_econv(const float* __restrict__ g1,
                                               const float* __restrict__ p1,
                                               const int* __restrict__ i50,
                                               const unsigned short* __restrict__ w2h,
                                               const unsigned short* __restrict__ w2l,
                                               const float* __restrict__ bb2,
                                               float* __restrict__ cin){
  __shared__ __align__(16) unsigned short BH[2*64*136];   // W2 hi | lo, row stride 136
  unsigned short* bhi = BH;
  unsigned short* blo = BH + 64*136;
  int tid = threadIdx.x, w = tid >> 6, lane = tid & 63;
  int nl = lane & 15, quad = lane >> 4;
  for (int idx = tid; idx < 8192; idx += 512){
    int row = idx >> 7, k = idx & 127;
    bhi[row*136 + k] = w2h[idx];
    blo[row*136 + k] = w2l[idx];
  }
  __syncthreads();

  int gq = blockIdx.x*8 + w;
  int b = gq >> 13;
  const int* jrow = i50 + (size_t)gq*50;
  const float* pr = p1 + (size_t)gq*112;
  float4 pf[8];
  #pragma unroll
  for (int ks = 0; ks < 4; ++ks){
    if (ks < 3 || quad < 2){
      pf[2*ks]   = *(const float4*)(pr + ks*32 + quad*8);
      pf[2*ks+1] = *(const float4*)(pr + ks*32 + quad*8 + 4);
    } else {
      pf[2*ks] = make_float4(0.f,0.f,0.f,0.f); pf[2*ks+1] = make_float4(0.f,0.f,0.f,0.f);
    }
  }
  float m4[4] = {-3.4e38f, -3.4e38f, -3.4e38f, -3.4e38f};

  for (int rt = 0; rt < 4; ++rt){
    int e = rt*16 + nl;
    int j = jrow[e < 50 ? e : 49];
    const float* gr = g1 + (size_t)(b*8192 + j)*112;
    s16x8 ah[4], al[4];
    #pragma unroll
    for (int ks = 0; ks < 4; ++ks){
      if (ks == 3 && quad >= 2){
        #pragma unroll
        for (int i = 0; i < 8; ++i){ ah[3][i] = 0; al[3][i] = 0; }
      } else {
        int off = ks*32 + quad*8;
        float4 g0  = *(const float4*)(gr + off);
        float4 g1v = *(const float4*)(gr + off + 4);
        float4 p0v = pf[2*ks], p1v = pf[2*ks+1];
        float tv[8] = { leaky(g0.x+p0v.x),  leaky(g0.y+p0v.y),  leaky(g0.z+p0v.z),  leaky(g0.w+p0v.w),
                        leaky(g1v.x+p1v.x), leaky(g1v.y+p1v.y), leaky(g1v.z+p1v.z), leaky(g1v.w+p1v.w) };
        #pragma unroll
        for (int i = 0; i < 8; ++i){
          unsigned bits = __float_as_uint(tv[i]);
          ah[ks][i] = (short)(bits >> 16);
          float hv = __uint_as_float(bits & 0xFFFF0000u);
          al[ks][i] = (short)rne_bf16(tv[i] - hv);
        }
      }
    }
    f32x4 C[4] = {{0.f,0.f,0.f,0.f},{0.f,0.f,0.f,0.f},{0.f,0.f,0.f,0.f},{0.f,0.f,0.f,0.f}};
    #pragma unroll
    for (int ks = 0; ks < 4; ++ks){
      int ko = ks*64 + quad*16;
      #pragma unroll
      for (int ct = 0; ct < 4; ++ct){
        const char* rp = (const char*)bhi + (ct*16 + nl)*272 + ko;
        s16x8 bh  = *(const s16x8*)(rp);
        s16x8 blv = *(const s16x8*)(rp + 64*136*2);
        C[ct] = __builtin_amdgcn_mfma_f32_16x16x32_bf16(ah[ks], bh,  C[ct], 0, 0, 0);
        C[ct] = __builtin_amdgcn_mfma_f32_16x16x32_bf16(al[ks], bh,  C[ct], 0, 0, 0);
        C[ct] = __builtin_amdgcn_mfma_f32_16x16x32_bf16(ah[ks], blv, C[ct], 0, 0, 0);
      }
    }
    if (rt < 3){
      #pragma unroll
      for (int ct = 0; ct < 4; ++ct)
        #pragma unroll
        for (int r = 0; r < 4; ++r) m4[ct] = fmaxf(m4[ct], C[ct][r]);
    } else {
      if (quad == 0){
        #pragma unroll
        for (int ct = 0; ct < 4; ++ct){
          m4[ct] = fmaxf(m4[ct], C[ct][0]);
          m4[ct] = fmaxf(m4[ct], C[ct][1]);
        }
      }
    }
  }
  #pragma unroll
  for (int ct = 0; ct < 4; ++ct){
    m4[ct] = fmaxf(m4[ct], __shfl_xor(m4[ct], 16));
    m4[ct] = fmaxf(m4[ct], __shfl_xor(m4[ct], 32));
  }
  if (quad == 0){
    #pragma unroll
    for (int ct = 0; ct < 4; ++ct){
      int o = ct*16 + nl;
      cin[(size_t)gq*64 + o] = leaky(m4[ct] + bb2[o]);
    }
  }
}

// ---------------- downsample conv (1,3) stride (1,2) pad (0,1) ----------------
__global__ __launch_bounds__(256) void k_down(const float* __restrict__ cin,
                                              const float* __restrict__ wdt,
                                              const float* __restrict__ bias,
                                              float* __restrict__ outp){
  int blk = blockIdx.x;
  int b = blk >> 8, r = blk & 255, s = r >> 3, oq = r & 7;
  int t = threadIdx.x;
  __shared__ __align__(16) float L[34*68];
  for (int k = t; k < 34*64; k += 256){
    int rr = k >> 6, i = k & 63;
    int pp = oq*32 - 1 + rr;
    float v = 0.f;
    if (pp >= 0 && pp < 256) v = cin[(size_t)(b*8192 + s*256 + pp)*64 + i];
    L[rr*68 + i] = v;
  }
  __syncthreads();
  #pragma unroll
  for (int kk = 0; kk < 4; ++kk){
    int ow = kk*256 + t;
    int o = ow >> 4, wl = ow & 15;
    float acc = bias[o];
    #pragma unroll
    for (int tt = 0; tt < 3; ++tt){
      int rr = 2*wl + tt;
      const float4* lv4 = (const float4*)(L + rr*68);
      const float4* wv4 = (const float4*)(wdt + tt*4096 + o*64);
      #pragma unroll
      for (int i4 = 0; i4 < 16; ++i4){
        float4 lv = lv4[i4], wv = wv4[i4];
        acc += wv.x*lv.x + wv.y*lv.y + wv.z*lv.z + wv.w*lv.w;
      }
    }
    int w_ = oq*16 + wl;
    outp[16384 + (size_t)((b*64 + o)*32 + s)*128 + w_] = leaky(acc);
  }
}

extern "C" void kernel_launch(void* const* d_in, const int* in_sizes, int n_in,
                              void* d_out, int out_size, void* d_ws, size_t ws_size,
                              hipStream_t stream){
  (void)in_sizes; (void)n_in; (void)out_size; (void)ws_size;
  const float* sparse = (const float*)d_in[0];
  const float* dense  = (const float*)d_in[1];
  const float* spW1   = (const float*)d_in[2];
  const float* spb1   = (const float*)d_in[3];
  const float* spW2   = (const float*)d_in[4];
  const float* spb2   = (const float*)d_in[5];
  const float* dnW1   = (const float*)d_in[6];
  const float* dnb1   = (const float*)d_in[7];
  const float* dnW2   = (const float*)d_in[8];
  const float* dnb2   = (const float*)d_in[9];
  const float* dsW    = (const float*)d_in[10];
  const float* dsb    = (const float*)d_in[11];
  float* out = (float*)d_out;

  float* w    = (float*)d_ws;                  // 63.5 MB
  float* xt   = w;                             // 3,145,728
  float* x2   = w + 3145728;                   //    32,768
  float* g1   = w + 3178496;                   // 3,670,016 (stride 112)
  float* p1   = w + 6848512;                   // 3,670,016
  int*   i50  = (int*)(w + 10518528);          // 1,638,400
  float* cin  = w + 12156928;                  // 2,097,152
  float* xtsp = w + 14254080;                  //    12,288
  unsigned short* xtb = (unsigned short*)(w + 14266368);  // 3,145,728 u16
  unsigned short* w1h = (unsigned short*)(w + 15839232);  // 21504 u16
  unsigned short* w1l = (unsigned short*)(w + 15849984);
  unsigned short* w2h = (unsigned short*)(w + 15860736);  // 8192 u16
  unsigned short* w2l = (unsigned short*)(w + 15864832);
  float* wdt  = w + 15868928;                  // 12,288

  k_prep        <<<164,  256, 0, stream>>>(dnW1, dnW2, dsW, w1h, w1l, w2h, w2l, wdt);
  k_build_xt    <<<512,  256, 0, stream>>>(dense, sparse, xt, xtb, x2);
  k_sparse_union<<<128,  256, 0, stream>>>(sparse, dense, xtsp);
  k_sparse_gcn  <<<128,  192, 0, stream>>>(xtsp, spW1, spb1, spW2, spb2, out);
  k_knn         <<<512,  256, 0, stream>>>(xtb, x2, xt, i50);
  k_g1p1        <<<512,  256, 0, stream>>>(xt, w1h, w1l, dnb1, g1, p1);
  k_econv       <<<4096, 512, 0, stream>>>(g1, p1, i50, w2h, w2l, dnb2, cin);
  k_down        <<<1024, 256, 0, stream>>>(cin, wdt, dsb, out);
}